// Round 6
// baseline (242.579 us; speedup 1.0000x reference)
//
#include <hip/hip_runtime.h>

#define EPSF 1e-5f
#define NSEG 2048
#define NTHR 768     // 12 waves
#define NWAVE 12
#define NBLK 256
#define STRIDE 3072  // NBLK * NWAVE

typedef short s16x8 __attribute__((ext_vector_type(8)));
typedef float f32x16 __attribute__((ext_vector_type(16)));
typedef unsigned u32;

__device__ __forceinline__ u32 f2bfu(float f) {
  u32 u = __float_as_uint(f);
  u += 0x7FFFu + ((u >> 16) & 1u);  // RNE; no NaN/Inf in data
  return u >> 16;
}
__device__ __forceinline__ u32 pk2(float a, float b) {  // host-prep path only
  return f2bfu(a) | (f2bfu(b) << 16);
}
// v_cvt_pk_bf16_f32: dst = {lo=bf16(a), hi=bf16(b)} — 1 VALU op
__device__ __forceinline__ u32 cvtpk(float a, float b) {
  u32 r;
  asm("v_cvt_pk_bf16_f32 %0, %1, %2" : "=v"(r) : "v"(a), "v"(b));
  return r;
}
__device__ __forceinline__ float bf2f(u32 h) {
  return __uint_as_float(h << 16);
}

union FragU { s16x8 v; u32 u[4]; };

struct LayerP { const float *W, *b, *g, *be, *m, *v; };

__global__ void zero_kernel(uint4* __restrict__ p, int n16) {
  int i = blockIdx.x * blockDim.x + threadIdx.x;
  if (i < n16) p[i] = make_uint4(0u, 0u, 0u, 0u);
}

// Fold BN into weights: W'[c,k] = W[c,k]*s_c (bf16), bias'_c = b_c*s_c + be_c - m_c*s_c
__global__ void prep_kernel(LayerP p0, LayerP p1, LayerP p2,
                            unsigned short* __restrict__ wsW,
                            float* __restrict__ biasf) {
  const int L = blockIdx.x;
  LayerP p = (L == 0) ? p0 : ((L == 1) ? p1 : p2);
  const int t = threadIdx.x;
  uint2* wdst = (uint2*)(wsW + L * 16384);
  const float4* wsrc = (const float4*)p.W;
  for (int i = 0; i < 16; ++i) {
    int idx4 = t + i * 256;            // 4096 float4 = 128x128
    int c = idx4 >> 5;
    float s = p.g[c] * rsqrtf(p.v[c] + EPSF);
    float4 w = wsrc[idx4];
    wdst[idx4] = make_uint2(pk2(w.x * s, w.y * s), pk2(w.z * s, w.w * s));
  }
  if (t < 128) {
    float s = p.g[t] * rsqrtf(p.v[t] + EPSF);
    biasf[L * 128 + t] = p.b[t] * s + p.be[t] - p.m[t] * s;
  }
}

// Barrier-free persistent encoder: each wave owns independent 32-row tiles.
// LDS: [0,98304) swizzled weights (3 layers); [98304,147456) 12x4KB wave-private h3.
__global__ __launch_bounds__(NTHR)
void enc_kernel(const float* __restrict__ x, const int* __restrict__ batch,
                const unsigned short* __restrict__ wsW, const float* __restrict__ biasf,
                float* __restrict__ seg_sum, int* __restrict__ seg_max,
                u32* __restrict__ seg_cnt, int N, int ntiles) {
  __shared__ __attribute__((aligned(16))) unsigned char lds[98304 + NWAVE * 4096];
  __shared__ __attribute__((aligned(16))) float bias_lds[384];
  const int t = threadIdx.x;
  const int lane = t & 63, wv = t >> 6;
  const int l31 = lane & 31, hi = lane >> 5;
  const int swz = l31 & 15;
  const int xaddr = (lane ^ 32) << 2;  // ds_bpermute byte-addr of partner lane

  // one-time: stage weights global->LDS with chunk^row swizzle
  {
    const uint4* src = (const uint4*)wsW;
#pragma unroll
    for (int i = 0; i < 8; ++i) {
      int idx = t + i * NTHR;          // 6144 x 16B
      int byte = idx << 4;
      int dst = byte ^ (((byte >> 8) & 15) << 4);  // chunk ^= row&15
      *(uint4*)&lds[dst] = src[idx];
    }
  }
  if (t < 384) bias_lds[t] = biasf[t];
  __syncthreads();                      // the only block barrier

  const int hbase = 98304 + wv * 4096;
  const float4* x4 = (const float4*)x;
  const int g0 = blockIdx.x * NWAVE + wv;

  float4 xr[16];
  int sreg;
  {  // prologue prefetch (tile g0 always < ntiles: ntiles=15625 >= STRIDE)
    int r = g0 * 32 + l31;
    bool ok = r < N;
#pragma unroll
    for (int s = 0; s < 8; ++s) {
      size_t base = (size_t)r * 32 + s * 4 + hi * 2;
      xr[2 * s]     = ok ? x4[base]     : make_float4(0.f, 0.f, 0.f, 0.f);
      xr[2 * s + 1] = ok ? x4[base + 1] : make_float4(0.f, 0.f, 0.f, 0.f);
    }
    sreg = ok ? batch[r] : -1;
  }

  for (int tile = g0; tile < ntiles; tile += STRIDE) {
    // convert prefetched x -> B-fragments (lane = row l31, k = 16s+8hi+j)
    FragU frag[8];
#pragma unroll
    for (int s = 0; s < 8; ++s) {
      float4 a = xr[2 * s], b = xr[2 * s + 1];
      frag[s].u[0] = cvtpk(a.x, a.y);
      frag[s].u[1] = cvtpk(a.z, a.w);
      frag[s].u[2] = cvtpk(b.x, b.y);
      frag[s].u[3] = cvtpk(b.z, b.w);
    }
    const int scur = sreg;
    {  // issue prefetch for next tile (lands under 3 layers of compute)
      int nt = tile + STRIDE;
      int r = nt * 32 + l31;
      bool ok = (nt < ntiles) && (r < N);
#pragma unroll
      for (int s = 0; s < 8; ++s) {
        size_t base = (size_t)r * 32 + s * 4 + hi * 2;
        xr[2 * s]     = ok ? x4[base]     : make_float4(0.f, 0.f, 0.f, 0.f);
        xr[2 * s + 1] = ok ? x4[base + 1] : make_float4(0.f, 0.f, 0.f, 0.f);
      }
      sreg = ok ? batch[r] : -1;
    }

    f32x16 accs[4];
#pragma unroll
    for (int L = 0; L < 3; ++L) {
      const int wb = L * 32768 + l31 * 256;
#pragma unroll
      for (int cg = 0; cg < 4; ++cg) {
        f32x16 z = {0,0,0,0,0,0,0,0,0,0,0,0,0,0,0,0};
        accs[cg] = z;
      }
#pragma unroll
      for (int s = 0; s < 8; ++s) {
#pragma unroll
        for (int cg = 0; cg < 4; ++cg) {
          const s16x8 a =
              *(const s16x8*)&lds[wb + cg * 8192 + (((2 * s + hi) ^ swz) << 4)];
          accs[cg] = __builtin_amdgcn_mfma_f32_32x32x16_bf16(a, frag[s].v, accs[cg], 0, 0, 0);
        }
      }
      if (L < 2) {
        // bias + relu, pack (cvt_pk), half-exchange via ds_bpermute
#pragma unroll
        for (int cg = 0; cg < 4; ++cg) {
          float tr[16];
#pragma unroll
          for (int q = 0; q < 4; ++q) {
            int ch = cg * 32 + 4 * hi + 8 * q;   // C/D: c = (r&3) + 8*(r>>2) + 4*hi
            const float4 bb = *(const float4*)&bias_lds[L * 128 + ch];
            tr[4 * q + 0] = fmaxf(accs[cg][4 * q + 0] + bb.x, 0.f);
            tr[4 * q + 1] = fmaxf(accs[cg][4 * q + 1] + bb.y, 0.f);
            tr[4 * q + 2] = fmaxf(accs[cg][4 * q + 2] + bb.z, 0.f);
            tr[4 * q + 3] = fmaxf(accs[cg][4 * q + 3] + bb.w, 0.f);
          }
#pragma unroll
          for (int kh = 0; kh < 2; ++kh) {
            u32 pw0 = cvtpk(tr[8 * kh + 0], tr[8 * kh + 1]);  // c = 16kh+{0,1}+4hi'
            u32 pw1 = cvtpk(tr[8 * kh + 2], tr[8 * kh + 3]);  // c = 16kh+{2,3}+4hi'
            u32 pu0 = cvtpk(tr[8 * kh + 4], tr[8 * kh + 5]);  // c = 16kh+8+{0,1}+4hi'
            u32 pu1 = cvtpk(tr[8 * kh + 6], tr[8 * kh + 7]);  // c = 16kh+8+{2,3}+4hi'
            u32 cw0 = (u32)__builtin_amdgcn_ds_bpermute(xaddr, (int)pw0);
            u32 cw1 = (u32)__builtin_amdgcn_ds_bpermute(xaddr, (int)pw1);
            u32 cu0 = (u32)__builtin_amdgcn_ds_bpermute(xaddr, (int)pu0);
            u32 cu1 = (u32)__builtin_amdgcn_ds_bpermute(xaddr, (int)pu1);
            // target frag[2cg+kh]: u[0,1] = c 16kh+8hi+{0..3}, u[2,3] = +{4..7}
            frag[2 * cg + kh].u[0] = hi ? cu0 : pw0;
            frag[2 * cg + kh].u[1] = hi ? cu1 : pw1;
            frag[2 * cg + kh].u[2] = hi ? pu0 : cw0;
            frag[2 * cg + kh].u[3] = hi ? pu1 : cw1;
          }
        }
      }
    }

    // ---- segment phase: wave-private LDS, two 16-row halves, no barriers ----
    float s0 = 0.f, s1 = 0.f, m0 = 0.f, m1 = 0.f;
    int cur = -1, cnt = 0;
#pragma unroll
    for (int half = 0; half < 2; ++half) {
      if ((l31 >> 4) == half) {  // write my row (l31) with bias+relu applied
#pragma unroll
        for (int cg = 0; cg < 4; ++cg)
#pragma unroll
          for (int q = 0; q < 4; ++q) {
            int ch = cg * 32 + 4 * hi + 8 * q;
            const float4 bb = *(const float4*)&bias_lds[256 + ch];
            float e0 = fmaxf(accs[cg][4 * q + 0] + bb.x, 0.f);
            float e1 = fmaxf(accs[cg][4 * q + 1] + bb.y, 0.f);
            float e2 = fmaxf(accs[cg][4 * q + 2] + bb.z, 0.f);
            float e3 = fmaxf(accs[cg][4 * q + 3] + bb.w, 0.f);
            *(uint2*)&lds[hbase + (l31 & 15) * 256 + ((((cg << 2) + q) ^ swz) << 4) + hi * 8] =
                make_uint2(cvtpk(e0, e1), cvtpk(e2, e3));
          }
      }
      const int rbase = half * 16;
#pragma unroll
      for (int r = 0; r < 16; ++r) {
        int sid = __builtin_amdgcn_readlane(scur, rbase + r);
        if (sid != cur) {
          if (cur >= 0) {
            atomicAdd(&seg_sum[cur * 128 + 2 * lane], s0);
            atomicAdd(&seg_sum[cur * 128 + 2 * lane + 1], s1);
            atomicMax(&seg_max[cur * 128 + 2 * lane], __float_as_int(m0));
            atomicMax(&seg_max[cur * 128 + 2 * lane + 1], __float_as_int(m1));
            if (lane == 0) atomicAdd(&seg_cnt[cur], (u32)cnt);
          }
          s0 = s1 = m0 = m1 = 0.f; cnt = 0; cur = sid;
        }
        if (cur >= 0) {
          u32 pv = *(const u32*)&lds[hbase + r * 256 + ((((lane >> 2) ^ r) & 15) << 4) +
                                     (lane & 3) * 4];
          float v0 = bf2f(pv & 0xffffu);
          float v1 = bf2f(pv >> 16);
          s0 += v0; s1 += v1;
          m0 = fmaxf(m0, v0); m1 = fmaxf(m1, v1);
          ++cnt;
        }
      }
    }
    if (cur >= 0) {  // final flush
      atomicAdd(&seg_sum[cur * 128 + 2 * lane], s0);
      atomicAdd(&seg_sum[cur * 128 + 2 * lane + 1], s1);
      atomicMax(&seg_max[cur * 128 + 2 * lane], __float_as_int(m0));
      atomicMax(&seg_max[cur * 128 + 2 * lane + 1], __float_as_int(m1));
      if (lane == 0) atomicAdd(&seg_cnt[cur], (u32)cnt);
    }
  }
}

// out[s,o] = BN( [sum|max|mean] @ Wo^T + bo )
__global__ __launch_bounds__(128)
void proj_kernel(const float* __restrict__ seg_sum, const unsigned* __restrict__ seg_max,
                 const u32* __restrict__ seg_cnt,
                 const float* __restrict__ Wo, const float* __restrict__ bo,
                 const float* __restrict__ go, const float* __restrict__ beo,
                 const float* __restrict__ mo, const float* __restrict__ vo,
                 float* __restrict__ out) {
  __shared__ __attribute__((aligned(16))) float agg[384];
  __shared__ float part[64];
  const int s = blockIdx.x, t = threadIdx.x;
  float cinv = 1.f / fmaxf((float)seg_cnt[s], 1.f);
  for (int i = t; i < 384; i += 128) {
    float v;
    if (i < 128)      v = seg_sum[s * 128 + i];
    else if (i < 256) v = __uint_as_float(seg_max[s * 128 + i - 128]);
    else              v = seg_sum[s * 128 + i - 256] * cinv;
    agg[i] = v;
  }
  __syncthreads();
  const int o = t & 63, hf = t >> 6;
  const float4* wrow = (const float4*)(Wo + o * 384 + hf * 192);
  float acc = 0.f;
#pragma unroll 8
  for (int k4 = 0; k4 < 48; ++k4) {
    float4 w = wrow[k4];
    float4 a = *(const float4*)&agg[hf * 192 + k4 * 4];
    acc += w.x * a.x + w.y * a.y + w.z * a.z + w.w * a.w;
  }
  if (hf) part[o] = acc;
  __syncthreads();
  if (!hf) {
    acc += part[o];
    float sc = go[o] * rsqrtf(vo[o] + EPSF);
    out[s * 64 + o] = (acc + bo[o] - mo[o]) * sc + beo[o];
  }
}

extern "C" void kernel_launch(void* const* d_in, const int* in_sizes, int n_in,
                              void* d_out, int out_size, void* d_ws, size_t ws_size,
                              hipStream_t stream) {
  (void)n_in; (void)out_size; (void)ws_size;
  const float* x = (const float*)d_in[0];
  const int* batch = (const int*)d_in[1];
  LayerP P0{(const float*)d_in[2],  (const float*)d_in[3],  (const float*)d_in[4],
            (const float*)d_in[5],  (const float*)d_in[6],  (const float*)d_in[7]};
  LayerP P1{(const float*)d_in[8],  (const float*)d_in[9],  (const float*)d_in[10],
            (const float*)d_in[11], (const float*)d_in[12], (const float*)d_in[13]};
  LayerP P2{(const float*)d_in[14], (const float*)d_in[15], (const float*)d_in[16],
            (const float*)d_in[17], (const float*)d_in[18], (const float*)d_in[19]};
  const float* Wo  = (const float*)d_in[20];
  const float* bo  = (const float*)d_in[21];
  const float* go  = (const float*)d_in[22];
  const float* beo = (const float*)d_in[23];
  const float* mo  = (const float*)d_in[24];
  const float* vo  = (const float*)d_in[25];
  const int N = in_sizes[0] / 128;

  char* ws = (char*)d_ws;
  float* seg_sum = (float*)ws;                         // 1 MiB
  int*   seg_max = (int*)(ws + (1u << 20));            // 1 MiB (float bits, >=0)
  u32*   seg_cnt = (u32*)(ws + (2u << 20));            // 8 KiB
  unsigned short* wsW = (unsigned short*)(ws + (2u << 20) + 8192);  // 96 KiB
  float* biasf = (float*)(ws + (2u << 20) + 8192 + 98304);          // 1.5 KiB

  const int n16 = ((2 << 20) + 8192) / 16;
  zero_kernel<<<(n16 + 255) / 256, 256, 0, stream>>>((uint4*)d_ws, n16);
  prep_kernel<<<3, 256, 0, stream>>>(P0, P1, P2, wsW, biasf);
  const int ntiles = (N + 31) / 32;
  enc_kernel<<<NBLK, NTHR, 0, stream>>>(x, batch, wsW, biasf, seg_sum, seg_max, seg_cnt,
                                        N, ntiles);
  proj_kernel<<<NSEG, 128, 0, stream>>>(seg_sum, (const unsigned*)seg_max, seg_cnt,
                                        Wo, bo, go, beo, mo, vo, (float*)d_out);
}

// Round 7
// 241.973 us; speedup vs baseline: 1.0025x; 1.0025x over previous
//
#include <hip/hip_runtime.h>

#define EPSF 1e-5f
#define NSEG 2048
#define NTHR 768     // 12 waves
#define NWAVE 12
#define NBLK 256
#define STRIDE 3072  // NBLK * NWAVE

typedef short s16x8 __attribute__((ext_vector_type(8)));
typedef float f32x16 __attribute__((ext_vector_type(16)));
typedef unsigned u32;

__device__ __forceinline__ u32 f2bfu(float f) {
  u32 u = __float_as_uint(f);
  u += 0x7FFFu + ((u >> 16) & 1u);  // RNE; no NaN/Inf in data
  return u >> 16;
}
__device__ __forceinline__ u32 pk2(float a, float b) {  // host-prep path only
  return f2bfu(a) | (f2bfu(b) << 16);
}
// v_cvt_pk_bf16_f32: dst = {lo=bf16(a), hi=bf16(b)} — 1 VALU op
__device__ __forceinline__ u32 cvtpk(float a, float b) {
  u32 r;
  asm("v_cvt_pk_bf16_f32 %0, %1, %2" : "=v"(r) : "v"(a), "v"(b));
  return r;
}
__device__ __forceinline__ float bf2f(u32 h) {
  return __uint_as_float(h << 16);
}

union FragU { s16x8 v; u32 u[4]; };

struct LayerP { const float *W, *b, *g, *be, *m, *v; };

__global__ void zero_kernel(uint4* __restrict__ p, int n16) {
  int i = blockIdx.x * blockDim.x + threadIdx.x;
  if (i < n16) p[i] = make_uint4(0u, 0u, 0u, 0u);
}

// Fold BN into weights: W'[c,k] = W[c,k]*s_c (bf16), bias'_c = b_c*s_c + be_c - m_c*s_c
__global__ void prep_kernel(LayerP p0, LayerP p1, LayerP p2,
                            unsigned short* __restrict__ wsW,
                            float* __restrict__ biasf) {
  const int L = blockIdx.x;
  LayerP p = (L == 0) ? p0 : ((L == 1) ? p1 : p2);
  const int t = threadIdx.x;
  uint2* wdst = (uint2*)(wsW + L * 16384);
  const float4* wsrc = (const float4*)p.W;
  for (int i = 0; i < 16; ++i) {
    int idx4 = t + i * 256;            // 4096 float4 = 128x128
    int c = idx4 >> 5;
    float s = p.g[c] * rsqrtf(p.v[c] + EPSF);
    float4 w = wsrc[idx4];
    wdst[idx4] = make_uint2(pk2(w.x * s, w.y * s), pk2(w.z * s, w.w * s));
  }
  if (t < 128) {
    float s = p.g[t] * rsqrtf(p.v[t] + EPSF);
    biasf[L * 128 + t] = p.b[t] * s + p.be[t] - p.m[t] * s;
  }
}

// Barrier-free persistent encoder: each wave owns independent 32-row tiles.
// LDS: [0,98304) swizzled weights (3 layers); [98304,147456) 12x4KB wave-private h3.
// __launch_bounds__(768, 3): min 3 waves/SIMD -> VGPR cap 170 (kernel needs ~128-160;
// without the min-waves arg the compiler picked 84 VGPR and spilled ~125MB/launch).
__global__ __launch_bounds__(NTHR, 3)
void enc_kernel(const float* __restrict__ x, const int* __restrict__ batch,
                const unsigned short* __restrict__ wsW, const float* __restrict__ biasf,
                float* __restrict__ seg_sum, int* __restrict__ seg_max,
                u32* __restrict__ seg_cnt, int N, int ntiles) {
  __shared__ __attribute__((aligned(16))) unsigned char lds[98304 + NWAVE * 4096];
  __shared__ __attribute__((aligned(16))) float bias_lds[384];
  const int t = threadIdx.x;
  const int lane = t & 63, wv = t >> 6;
  const int l31 = lane & 31, hi = lane >> 5;
  const int swz = l31 & 15;
  const int xaddr = (lane ^ 32) << 2;  // ds_bpermute byte-addr of partner lane

  // one-time: stage weights global->LDS with chunk^row swizzle
  {
    const uint4* src = (const uint4*)wsW;
#pragma unroll
    for (int i = 0; i < 8; ++i) {
      int idx = t + i * NTHR;          // 6144 x 16B
      int byte = idx << 4;
      int dst = byte ^ (((byte >> 8) & 15) << 4);  // chunk ^= row&15
      *(uint4*)&lds[dst] = src[idx];
    }
  }
  if (t < 384) bias_lds[t] = biasf[t];
  __syncthreads();                      // the only block barrier

  const int hbase = 98304 + wv * 4096;
  const float4* x4 = (const float4*)x;
  const int g0 = blockIdx.x * NWAVE + wv;

  float4 xr[16];
  int sreg;
  {  // prologue prefetch (tile g0 always < ntiles: ntiles=15625 >= STRIDE)
    int r = g0 * 32 + l31;
    bool ok = r < N;
#pragma unroll
    for (int s = 0; s < 8; ++s) {
      size_t base = (size_t)r * 32 + s * 4 + hi * 2;
      xr[2 * s]     = ok ? x4[base]     : make_float4(0.f, 0.f, 0.f, 0.f);
      xr[2 * s + 1] = ok ? x4[base + 1] : make_float4(0.f, 0.f, 0.f, 0.f);
    }
    sreg = ok ? batch[r] : -1;
  }

  for (int tile = g0; tile < ntiles; tile += STRIDE) {
    // convert prefetched x -> B-fragments (lane = row l31, k = 16s+8hi+j)
    FragU frag[8];
#pragma unroll
    for (int s = 0; s < 8; ++s) {
      float4 a = xr[2 * s], b = xr[2 * s + 1];
      frag[s].u[0] = cvtpk(a.x, a.y);
      frag[s].u[1] = cvtpk(a.z, a.w);
      frag[s].u[2] = cvtpk(b.x, b.y);
      frag[s].u[3] = cvtpk(b.z, b.w);
    }
    const int scur = sreg;
    {  // issue prefetch for next tile (lands under 3 layers of compute)
      int nt = tile + STRIDE;
      int r = nt * 32 + l31;
      bool ok = (nt < ntiles) && (r < N);
#pragma unroll
      for (int s = 0; s < 8; ++s) {
        size_t base = (size_t)r * 32 + s * 4 + hi * 2;
        xr[2 * s]     = ok ? x4[base]     : make_float4(0.f, 0.f, 0.f, 0.f);
        xr[2 * s + 1] = ok ? x4[base + 1] : make_float4(0.f, 0.f, 0.f, 0.f);
      }
      sreg = ok ? batch[r] : -1;
    }

    f32x16 accs[4];
#pragma unroll
    for (int L = 0; L < 3; ++L) {
      const int wb = L * 32768 + l31 * 256;
#pragma unroll
      for (int cg = 0; cg < 4; ++cg) {
        f32x16 z = {0,0,0,0,0,0,0,0,0,0,0,0,0,0,0,0};
        accs[cg] = z;
      }
#pragma unroll
      for (int s = 0; s < 8; ++s) {
#pragma unroll
        for (int cg = 0; cg < 4; ++cg) {
          const s16x8 a =
              *(const s16x8*)&lds[wb + cg * 8192 + (((2 * s + hi) ^ swz) << 4)];
          accs[cg] = __builtin_amdgcn_mfma_f32_32x32x16_bf16(a, frag[s].v, accs[cg], 0, 0, 0);
        }
      }
      if (L < 2) {
        // bias + relu, pack (cvt_pk), half-exchange via ds_bpermute
#pragma unroll
        for (int cg = 0; cg < 4; ++cg) {
          float tr[16];
#pragma unroll
          for (int q = 0; q < 4; ++q) {
            int ch = cg * 32 + 4 * hi + 8 * q;   // C/D: c = (r&3) + 8*(r>>2) + 4*hi
            const float4 bb = *(const float4*)&bias_lds[L * 128 + ch];
            tr[4 * q + 0] = fmaxf(accs[cg][4 * q + 0] + bb.x, 0.f);
            tr[4 * q + 1] = fmaxf(accs[cg][4 * q + 1] + bb.y, 0.f);
            tr[4 * q + 2] = fmaxf(accs[cg][4 * q + 2] + bb.z, 0.f);
            tr[4 * q + 3] = fmaxf(accs[cg][4 * q + 3] + bb.w, 0.f);
          }
#pragma unroll
          for (int kh = 0; kh < 2; ++kh) {
            u32 pw0 = cvtpk(tr[8 * kh + 0], tr[8 * kh + 1]);  // c = 16kh+{0,1}+4hi'
            u32 pw1 = cvtpk(tr[8 * kh + 2], tr[8 * kh + 3]);  // c = 16kh+{2,3}+4hi'
            u32 pu0 = cvtpk(tr[8 * kh + 4], tr[8 * kh + 5]);  // c = 16kh+8+{0,1}+4hi'
            u32 pu1 = cvtpk(tr[8 * kh + 6], tr[8 * kh + 7]);  // c = 16kh+8+{2,3}+4hi'
            u32 cw0 = (u32)__builtin_amdgcn_ds_bpermute(xaddr, (int)pw0);
            u32 cw1 = (u32)__builtin_amdgcn_ds_bpermute(xaddr, (int)pw1);
            u32 cu0 = (u32)__builtin_amdgcn_ds_bpermute(xaddr, (int)pu0);
            u32 cu1 = (u32)__builtin_amdgcn_ds_bpermute(xaddr, (int)pu1);
            // target frag[2cg+kh]: u[0,1] = c 16kh+8hi+{0..3}, u[2,3] = +{4..7}
            frag[2 * cg + kh].u[0] = hi ? cu0 : pw0;
            frag[2 * cg + kh].u[1] = hi ? cu1 : pw1;
            frag[2 * cg + kh].u[2] = hi ? pu0 : cw0;
            frag[2 * cg + kh].u[3] = hi ? pu1 : cw1;
          }
        }
      }
    }

    // ---- segment phase: wave-private LDS, two 16-row halves, no barriers ----
    float s0 = 0.f, s1 = 0.f, m0 = 0.f, m1 = 0.f;
    int cur = -1, cnt = 0;
#pragma unroll
    for (int half = 0; half < 2; ++half) {
      if ((l31 >> 4) == half) {  // write my row (l31) with bias+relu applied
#pragma unroll
        for (int cg = 0; cg < 4; ++cg)
#pragma unroll
          for (int q = 0; q < 4; ++q) {
            int ch = cg * 32 + 4 * hi + 8 * q;
            const float4 bb = *(const float4*)&bias_lds[256 + ch];
            float e0 = fmaxf(accs[cg][4 * q + 0] + bb.x, 0.f);
            float e1 = fmaxf(accs[cg][4 * q + 1] + bb.y, 0.f);
            float e2 = fmaxf(accs[cg][4 * q + 2] + bb.z, 0.f);
            float e3 = fmaxf(accs[cg][4 * q + 3] + bb.w, 0.f);
            *(uint2*)&lds[hbase + (l31 & 15) * 256 + ((((cg << 2) + q) ^ swz) << 4) + hi * 8] =
                make_uint2(cvtpk(e0, e1), cvtpk(e2, e3));
          }
      }
      const int rbase = half * 16;
#pragma unroll
      for (int r = 0; r < 16; ++r) {
        int sid = __builtin_amdgcn_readlane(scur, rbase + r);
        if (sid != cur) {
          if (cur >= 0) {
            atomicAdd(&seg_sum[cur * 128 + 2 * lane], s0);
            atomicAdd(&seg_sum[cur * 128 + 2 * lane + 1], s1);
            atomicMax(&seg_max[cur * 128 + 2 * lane], __float_as_int(m0));
            atomicMax(&seg_max[cur * 128 + 2 * lane + 1], __float_as_int(m1));
            if (lane == 0) atomicAdd(&seg_cnt[cur], (u32)cnt);
          }
          s0 = s1 = m0 = m1 = 0.f; cnt = 0; cur = sid;
        }
        if (cur >= 0) {
          u32 pv = *(const u32*)&lds[hbase + r * 256 + ((((lane >> 2) ^ r) & 15) << 4) +
                                     (lane & 3) * 4];
          float v0 = bf2f(pv & 0xffffu);
          float v1 = bf2f(pv >> 16);
          s0 += v0; s1 += v1;
          m0 = fmaxf(m0, v0); m1 = fmaxf(m1, v1);
          ++cnt;
        }
      }
    }
    if (cur >= 0) {  // final flush
      atomicAdd(&seg_sum[cur * 128 + 2 * lane], s0);
      atomicAdd(&seg_sum[cur * 128 + 2 * lane + 1], s1);
      atomicMax(&seg_max[cur * 128 + 2 * lane], __float_as_int(m0));
      atomicMax(&seg_max[cur * 128 + 2 * lane + 1], __float_as_int(m1));
      if (lane == 0) atomicAdd(&seg_cnt[cur], (u32)cnt);
    }
  }
}

// out[s,o] = BN( [sum|max|mean] @ Wo^T + bo )
__global__ __launch_bounds__(128)
void proj_kernel(const float* __restrict__ seg_sum, const unsigned* __restrict__ seg_max,
                 const u32* __restrict__ seg_cnt,
                 const float* __restrict__ Wo, const float* __restrict__ bo,
                 const float* __restrict__ go, const float* __restrict__ beo,
                 const float* __restrict__ mo, const float* __restrict__ vo,
                 float* __restrict__ out) {
  __shared__ __attribute__((aligned(16))) float agg[384];
  __shared__ float part[64];
  const int s = blockIdx.x, t = threadIdx.x;
  float cinv = 1.f / fmaxf((float)seg_cnt[s], 1.f);
  for (int i = t; i < 384; i += 128) {
    float v;
    if (i < 128)      v = seg_sum[s * 128 + i];
    else if (i < 256) v = __uint_as_float(seg_max[s * 128 + i - 128]);
    else              v = seg_sum[s * 128 + i - 256] * cinv;
    agg[i] = v;
  }
  __syncthreads();
  const int o = t & 63, hf = t >> 6;
  const float4* wrow = (const float4*)(Wo + o * 384 + hf * 192);
  float acc = 0.f;
#pragma unroll 8
  for (int k4 = 0; k4 < 48; ++k4) {
    float4 w = wrow[k4];
    float4 a = *(const float4*)&agg[hf * 192 + k4 * 4];
    acc += w.x * a.x + w.y * a.y + w.z * a.z + w.w * a.w;
  }
  if (hf) part[o] = acc;
  __syncthreads();
  if (!hf) {
    acc += part[o];
    float sc = go[o] * rsqrtf(vo[o] + EPSF);
    out[s * 64 + o] = (acc + bo[o] - mo[o]) * sc + beo[o];
  }
}

extern "C" void kernel_launch(void* const* d_in, const int* in_sizes, int n_in,
                              void* d_out, int out_size, void* d_ws, size_t ws_size,
                              hipStream_t stream) {
  (void)n_in; (void)out_size; (void)ws_size;
  const float* x = (const float*)d_in[0];
  const int* batch = (const int*)d_in[1];
  LayerP P0{(const float*)d_in[2],  (const float*)d_in[3],  (const float*)d_in[4],
            (const float*)d_in[5],  (const float*)d_in[6],  (const float*)d_in[7]};
  LayerP P1{(const float*)d_in[8],  (const float*)d_in[9],  (const float*)d_in[10],
            (const float*)d_in[11], (const float*)d_in[12], (const float*)d_in[13]};
  LayerP P2{(const float*)d_in[14], (const float*)d_in[15], (const float*)d_in[16],
            (const float*)d_in[17], (const float*)d_in[18], (const float*)d_in[19]};
  const float* Wo  = (const float*)d_in[20];
  const float* bo  = (const float*)d_in[21];
  const float* go  = (const float*)d_in[22];
  const float* beo = (const float*)d_in[23];
  const float* mo  = (const float*)d_in[24];
  const float* vo  = (const float*)d_in[25];
  const int N = in_sizes[0] / 128;

  char* ws = (char*)d_ws;
  float* seg_sum = (float*)ws;                         // 1 MiB
  int*   seg_max = (int*)(ws + (1u << 20));            // 1 MiB (float bits, >=0)
  u32*   seg_cnt = (u32*)(ws + (2u << 20));            // 8 KiB
  unsigned short* wsW = (unsigned short*)(ws + (2u << 20) + 8192);  // 96 KiB
  float* biasf = (float*)(ws + (2u << 20) + 8192 + 98304);          // 1.5 KiB

  const int n16 = ((2 << 20) + 8192) / 16;
  zero_kernel<<<(n16 + 255) / 256, 256, 0, stream>>>((uint4*)d_ws, n16);
  prep_kernel<<<3, 256, 0, stream>>>(P0, P1, P2, wsW, biasf);
  const int ntiles = (N + 31) / 32;
  enc_kernel<<<NBLK, NTHR, 0, stream>>>(x, batch, wsW, biasf, seg_sum, seg_max, seg_cnt,
                                        N, ntiles);
  proj_kernel<<<NSEG, 128, 0, stream>>>(seg_sum, (const unsigned*)seg_max, seg_cnt,
                                        Wo, bo, go, beo, mo, vo, (float*)d_out);
}

// Round 8
// 192.953 us; speedup vs baseline: 1.2572x; 1.2541x over previous
//
#include <hip/hip_runtime.h>

#define EPSF 1e-5f
#define NSEG 2048
#define NTHR 768     // 12 waves
#define NWAVE 12
#define NBLK 256
#define STRIDE 3072  // NBLK * NWAVE

typedef short s16x8 __attribute__((ext_vector_type(8)));
typedef float f32x16 __attribute__((ext_vector_type(16)));
typedef unsigned u32;

__device__ __forceinline__ u32 f2bfu(float f) {
  u32 u = __float_as_uint(f);
  u += 0x7FFFu + ((u >> 16) & 1u);  // RNE; no NaN/Inf in data
  return u >> 16;
}
__device__ __forceinline__ u32 pk2(float a, float b) {  // host-prep path only
  return f2bfu(a) | (f2bfu(b) << 16);
}
// v_cvt_pk_bf16_f32: dst = {lo=bf16(a), hi=bf16(b)} — 1 VALU op
__device__ __forceinline__ u32 cvtpk(float a, float b) {
  u32 r;
  asm("v_cvt_pk_bf16_f32 %0, %1, %2" : "=v"(r) : "v"(a), "v"(b));
  return r;
}
__device__ __forceinline__ float bf2f(u32 h) {
  return __uint_as_float(h << 16);
}

union FragU { s16x8 v; u32 u[4]; };

struct LayerP { const float *W, *b, *g, *be, *m, *v; };

__global__ void zero_kernel(uint4* __restrict__ p, int n16) {
  int i = blockIdx.x * blockDim.x + threadIdx.x;
  if (i < n16) p[i] = make_uint4(0u, 0u, 0u, 0u);
}

// Fold BN into weights: W'[c,k] = W[c,k]*s_c (bf16), bias'_c = b_c*s_c + be_c - m_c*s_c
__global__ void prep_kernel(LayerP p0, LayerP p1, LayerP p2,
                            unsigned short* __restrict__ wsW,
                            float* __restrict__ biasf) {
  const int L = blockIdx.x;
  LayerP p = (L == 0) ? p0 : ((L == 1) ? p1 : p2);
  const int t = threadIdx.x;
  uint2* wdst = (uint2*)(wsW + L * 16384);
  const float4* wsrc = (const float4*)p.W;
  for (int i = 0; i < 16; ++i) {
    int idx4 = t + i * 256;            // 4096 float4 = 128x128
    int c = idx4 >> 5;
    float s = p.g[c] * rsqrtf(p.v[c] + EPSF);
    float4 w = wsrc[idx4];
    wdst[idx4] = make_uint2(pk2(w.x * s, w.y * s), pk2(w.z * s, w.w * s));
  }
  if (t < 128) {
    float s = p.g[t] * rsqrtf(p.v[t] + EPSF);
    biasf[L * 128 + t] = p.b[t] * s + p.be[t] - p.m[t] * s;
  }
}

// Barrier-free persistent encoder: each wave owns independent 32-row tiles.
// LDS: [0,98304) swizzled weights (3 layers); [98304,147456) 12x4KB wave-private h3.
// Prefetch for tile T+1 is issued AFTER tile T's layer compute (xr live only across
// the segment phase), keeping peak live regs ~135 (< 170 cap at 3 waves/SIMD).
// Issuing at tile top (rounds 6/7) made xr live across all 3 layers -> ~180 live ->
// scratch spill (FETCH +123MB, WRITE +48MB).
__global__ __launch_bounds__(NTHR, 3)
void enc_kernel(const float* __restrict__ x, const int* __restrict__ batch,
                const unsigned short* __restrict__ wsW, const float* __restrict__ biasf,
                float* __restrict__ seg_sum, int* __restrict__ seg_max,
                u32* __restrict__ seg_cnt, int N, int ntiles) {
  __shared__ __attribute__((aligned(16))) unsigned char lds[98304 + NWAVE * 4096];
  __shared__ __attribute__((aligned(16))) float bias_lds[384];
  const int t = threadIdx.x;
  const int lane = t & 63, wv = t >> 6;
  const int l31 = lane & 31, hi = lane >> 5;
  const int swz = l31 & 15;
  const int xaddr = (lane ^ 32) << 2;  // ds_bpermute byte-addr of partner lane

  // one-time: stage weights global->LDS with chunk^row swizzle
  {
    const uint4* src = (const uint4*)wsW;
#pragma unroll
    for (int i = 0; i < 8; ++i) {
      int idx = t + i * NTHR;          // 6144 x 16B
      int byte = idx << 4;
      int dst = byte ^ (((byte >> 8) & 15) << 4);  // chunk ^= row&15
      *(uint4*)&lds[dst] = src[idx];
    }
  }
  if (t < 384) bias_lds[t] = biasf[t];
  __syncthreads();                      // the only block barrier

  const int hbase = 98304 + wv * 4096;
  const float4* x4 = (const float4*)x;
  const int g0 = blockIdx.x * NWAVE + wv;

  float4 xr[16];
  int sreg;
  {  // prologue prefetch (tile g0 always < ntiles: ntiles=15625 >= STRIDE)
    int r = g0 * 32 + l31;
    bool ok = r < N;
#pragma unroll
    for (int s = 0; s < 8; ++s) {
      size_t base = (size_t)r * 32 + s * 4 + hi * 2;
      xr[2 * s]     = ok ? x4[base]     : make_float4(0.f, 0.f, 0.f, 0.f);
      xr[2 * s + 1] = ok ? x4[base + 1] : make_float4(0.f, 0.f, 0.f, 0.f);
    }
    sreg = ok ? batch[r] : -1;
  }

  for (int tile = g0; tile < ntiles; tile += STRIDE) {
    // convert prefetched x -> B-fragments (lane = row l31, k = 16s+8hi+j); xr dies here
    FragU frag[8];
#pragma unroll
    for (int s = 0; s < 8; ++s) {
      float4 a = xr[2 * s], b = xr[2 * s + 1];
      frag[s].u[0] = cvtpk(a.x, a.y);
      frag[s].u[1] = cvtpk(a.z, a.w);
      frag[s].u[2] = cvtpk(b.x, b.y);
      frag[s].u[3] = cvtpk(b.z, b.w);
    }
    const int scur = sreg;

    f32x16 accs[4];
#pragma unroll
    for (int L = 0; L < 3; ++L) {
      const int wb = L * 32768 + l31 * 256;
#pragma unroll
      for (int cg = 0; cg < 4; ++cg) {
        f32x16 z = {0,0,0,0,0,0,0,0,0,0,0,0,0,0,0,0};
        accs[cg] = z;
      }
#pragma unroll
      for (int s = 0; s < 8; ++s) {
#pragma unroll
        for (int cg = 0; cg < 4; ++cg) {
          const s16x8 a =
              *(const s16x8*)&lds[wb + cg * 8192 + (((2 * s + hi) ^ swz) << 4)];
          accs[cg] = __builtin_amdgcn_mfma_f32_32x32x16_bf16(a, frag[s].v, accs[cg], 0, 0, 0);
        }
      }
      if (L < 2) {
        // bias + relu, pack (cvt_pk), half-exchange via ds_bpermute
#pragma unroll
        for (int cg = 0; cg < 4; ++cg) {
          float tr[16];
#pragma unroll
          for (int q = 0; q < 4; ++q) {
            int ch = cg * 32 + 4 * hi + 8 * q;   // C/D: c = (r&3) + 8*(r>>2) + 4*hi
            const float4 bb = *(const float4*)&bias_lds[L * 128 + ch];
            tr[4 * q + 0] = fmaxf(accs[cg][4 * q + 0] + bb.x, 0.f);
            tr[4 * q + 1] = fmaxf(accs[cg][4 * q + 1] + bb.y, 0.f);
            tr[4 * q + 2] = fmaxf(accs[cg][4 * q + 2] + bb.z, 0.f);
            tr[4 * q + 3] = fmaxf(accs[cg][4 * q + 3] + bb.w, 0.f);
          }
#pragma unroll
          for (int kh = 0; kh < 2; ++kh) {
            u32 pw0 = cvtpk(tr[8 * kh + 0], tr[8 * kh + 1]);  // c = 16kh+{0,1}+4hi'
            u32 pw1 = cvtpk(tr[8 * kh + 2], tr[8 * kh + 3]);  // c = 16kh+{2,3}+4hi'
            u32 pu0 = cvtpk(tr[8 * kh + 4], tr[8 * kh + 5]);  // c = 16kh+8+{0,1}+4hi'
            u32 pu1 = cvtpk(tr[8 * kh + 6], tr[8 * kh + 7]);  // c = 16kh+8+{2,3}+4hi'
            u32 cw0 = (u32)__builtin_amdgcn_ds_bpermute(xaddr, (int)pw0);
            u32 cw1 = (u32)__builtin_amdgcn_ds_bpermute(xaddr, (int)pw1);
            u32 cu0 = (u32)__builtin_amdgcn_ds_bpermute(xaddr, (int)pu0);
            u32 cu1 = (u32)__builtin_amdgcn_ds_bpermute(xaddr, (int)pu1);
            // target frag[2cg+kh]: u[0,1] = c 16kh+8hi+{0..3}, u[2,3] = +{4..7}
            frag[2 * cg + kh].u[0] = hi ? cu0 : pw0;
            frag[2 * cg + kh].u[1] = hi ? cu1 : pw1;
            frag[2 * cg + kh].u[2] = hi ? pu0 : cw0;
            frag[2 * cg + kh].u[3] = hi ? pu1 : cw1;
          }
        }
      }
    }

    // ---- issue next-tile prefetch HERE (frag dead; xr live only across seg phase) ----
    __builtin_amdgcn_sched_barrier(0);
    {
      int nt = tile + STRIDE;
      int r = nt * 32 + l31;
      bool ok = (nt < ntiles) && (r < N);
#pragma unroll
      for (int s = 0; s < 8; ++s) {
        size_t base = (size_t)r * 32 + s * 4 + hi * 2;
        xr[2 * s]     = ok ? x4[base]     : make_float4(0.f, 0.f, 0.f, 0.f);
        xr[2 * s + 1] = ok ? x4[base + 1] : make_float4(0.f, 0.f, 0.f, 0.f);
      }
      sreg = ok ? batch[r] : -1;
    }
    __builtin_amdgcn_sched_barrier(0);

    // ---- segment phase: wave-private LDS, two 16-row halves, no barriers ----
    float s0 = 0.f, s1 = 0.f, m0 = 0.f, m1 = 0.f;
    int cur = -1, cnt = 0;
#pragma unroll
    for (int half = 0; half < 2; ++half) {
      if ((l31 >> 4) == half) {  // write my row (l31) with bias+relu applied
#pragma unroll
        for (int cg = 0; cg < 4; ++cg)
#pragma unroll
          for (int q = 0; q < 4; ++q) {
            int ch = cg * 32 + 4 * hi + 8 * q;
            const float4 bb = *(const float4*)&bias_lds[256 + ch];
            float e0 = fmaxf(accs[cg][4 * q + 0] + bb.x, 0.f);
            float e1 = fmaxf(accs[cg][4 * q + 1] + bb.y, 0.f);
            float e2 = fmaxf(accs[cg][4 * q + 2] + bb.z, 0.f);
            float e3 = fmaxf(accs[cg][4 * q + 3] + bb.w, 0.f);
            *(uint2*)&lds[hbase + (l31 & 15) * 256 + ((((cg << 2) + q) ^ swz) << 4) + hi * 8] =
                make_uint2(cvtpk(e0, e1), cvtpk(e2, e3));
          }
      }
      const int rbase = half * 16;
#pragma unroll
      for (int r = 0; r < 16; ++r) {
        int sid = __builtin_amdgcn_readlane(scur, rbase + r);
        if (sid != cur) {
          if (cur >= 0) {
            atomicAdd(&seg_sum[cur * 128 + 2 * lane], s0);
            atomicAdd(&seg_sum[cur * 128 + 2 * lane + 1], s1);
            atomicMax(&seg_max[cur * 128 + 2 * lane], __float_as_int(m0));
            atomicMax(&seg_max[cur * 128 + 2 * lane + 1], __float_as_int(m1));
            if (lane == 0) atomicAdd(&seg_cnt[cur], (u32)cnt);
          }
          s0 = s1 = m0 = m1 = 0.f; cnt = 0; cur = sid;
        }
        if (cur >= 0) {
          u32 pv = *(const u32*)&lds[hbase + r * 256 + ((((lane >> 2) ^ r) & 15) << 4) +
                                     (lane & 3) * 4];
          float v0 = bf2f(pv & 0xffffu);
          float v1 = bf2f(pv >> 16);
          s0 += v0; s1 += v1;
          m0 = fmaxf(m0, v0); m1 = fmaxf(m1, v1);
          ++cnt;
        }
      }
    }
    if (cur >= 0) {  // final flush
      atomicAdd(&seg_sum[cur * 128 + 2 * lane], s0);
      atomicAdd(&seg_sum[cur * 128 + 2 * lane + 1], s1);
      atomicMax(&seg_max[cur * 128 + 2 * lane], __float_as_int(m0));
      atomicMax(&seg_max[cur * 128 + 2 * lane + 1], __float_as_int(m1));
      if (lane == 0) atomicAdd(&seg_cnt[cur], (u32)cnt);
    }
  }
}

// out[s,o] = BN( [sum|max|mean] @ Wo^T + bo )
__global__ __launch_bounds__(128)
void proj_kernel(const float* __restrict__ seg_sum, const unsigned* __restrict__ seg_max,
                 const u32* __restrict__ seg_cnt,
                 const float* __restrict__ Wo, const float* __restrict__ bo,
                 const float* __restrict__ go, const float* __restrict__ beo,
                 const float* __restrict__ mo, const float* __restrict__ vo,
                 float* __restrict__ out) {
  __shared__ __attribute__((aligned(16))) float agg[384];
  __shared__ float part[64];
  const int s = blockIdx.x, t = threadIdx.x;
  float cinv = 1.f / fmaxf((float)seg_cnt[s], 1.f);
  for (int i = t; i < 384; i += 128) {
    float v;
    if (i < 128)      v = seg_sum[s * 128 + i];
    else if (i < 256) v = __uint_as_float(seg_max[s * 128 + i - 128]);
    else              v = seg_sum[s * 128 + i - 256] * cinv;
    agg[i] = v;
  }
  __syncthreads();
  const int o = t & 63, hf = t >> 6;
  const float4* wrow = (const float4*)(Wo + o * 384 + hf * 192);
  float acc = 0.f;
#pragma unroll 8
  for (int k4 = 0; k4 < 48; ++k4) {
    float4 w = wrow[k4];
    float4 a = *(const float4*)&agg[hf * 192 + k4 * 4];
    acc += w.x * a.x + w.y * a.y + w.z * a.z + w.w * a.w;
  }
  if (hf) part[o] = acc;
  __syncthreads();
  if (!hf) {
    acc += part[o];
    float sc = go[o] * rsqrtf(vo[o] + EPSF);
    out[s * 64 + o] = (acc + bo[o] - mo[o]) * sc + beo[o];
  }
}

extern "C" void kernel_launch(void* const* d_in, const int* in_sizes, int n_in,
                              void* d_out, int out_size, void* d_ws, size_t ws_size,
                              hipStream_t stream) {
  (void)n_in; (void)out_size; (void)ws_size;
  const float* x = (const float*)d_in[0];
  const int* batch = (const int*)d_in[1];
  LayerP P0{(const float*)d_in[2],  (const float*)d_in[3],  (const float*)d_in[4],
            (const float*)d_in[5],  (const float*)d_in[6],  (const float*)d_in[7]};
  LayerP P1{(const float*)d_in[8],  (const float*)d_in[9],  (const float*)d_in[10],
            (const float*)d_in[11], (const float*)d_in[12], (const float*)d_in[13]};
  LayerP P2{(const float*)d_in[14], (const float*)d_in[15], (const float*)d_in[16],
            (const float*)d_in[17], (const float*)d_in[18], (const float*)d_in[19]};
  const float* Wo  = (const float*)d_in[20];
  const float* bo  = (const float*)d_in[21];
  const float* go  = (const float*)d_in[22];
  const float* beo = (const float*)d_in[23];
  const float* mo  = (const float*)d_in[24];
  const float* vo  = (const float*)d_in[25];
  const int N = in_sizes[0] / 128;

  char* ws = (char*)d_ws;
  float* seg_sum = (float*)ws;                         // 1 MiB
  int*   seg_max = (int*)(ws + (1u << 20));            // 1 MiB (float bits, >=0)
  u32*   seg_cnt = (u32*)(ws + (2u << 20));            // 8 KiB
  unsigned short* wsW = (unsigned short*)(ws + (2u << 20) + 8192);  // 96 KiB
  float* biasf = (float*)(ws + (2u << 20) + 8192 + 98304);          // 1.5 KiB

  const int n16 = ((2 << 20) + 8192) / 16;
  zero_kernel<<<(n16 + 255) / 256, 256, 0, stream>>>((uint4*)d_ws, n16);
  prep_kernel<<<3, 256, 0, stream>>>(P0, P1, P2, wsW, biasf);
  const int ntiles = (N + 31) / 32;
  enc_kernel<<<NBLK, NTHR, 0, stream>>>(x, batch, wsW, biasf, seg_sum, seg_max, seg_cnt,
                                        N, ntiles);
  proj_kernel<<<NSEG, 128, 0, stream>>>(seg_sum, (const unsigned*)seg_max, seg_cnt,
                                        Wo, bo, go, beo, mo, vo, (float*)d_out);
}

// Round 9
// 157.386 us; speedup vs baseline: 1.5413x; 1.2260x over previous
//
#include <hip/hip_runtime.h>

#define EPSF 1e-5f
#define NSEG 2048
#define NTHR 768     // 12 waves
#define NWAVE 12
#define NBLK 256
#define STRIDE 3072  // NBLK * NWAVE

typedef short s16x8 __attribute__((ext_vector_type(8)));
typedef float f32x16 __attribute__((ext_vector_type(16)));
typedef unsigned u32;

__device__ __forceinline__ u32 f2bfu(float f) {
  u32 u = __float_as_uint(f);
  u += 0x7FFFu + ((u >> 16) & 1u);  // RNE; no NaN/Inf in data
  return u >> 16;
}
__device__ __forceinline__ u32 pk2(float a, float b) {  // host-prep path only
  return f2bfu(a) | (f2bfu(b) << 16);
}
// v_cvt_pk_bf16_f32: dst = {lo=bf16(a), hi=bf16(b)} — 1 VALU op
__device__ __forceinline__ u32 cvtpk(float a, float b) {
  u32 r;
  asm("v_cvt_pk_bf16_f32 %0, %1, %2" : "=v"(r) : "v"(a), "v"(b));
  return r;
}
__device__ __forceinline__ float bf2f(u32 h) {
  return __uint_as_float(h << 16);
}

union FragU { s16x8 v; u32 u[4]; };

struct LayerP { const float *W, *b, *g, *be, *m, *v; };

__global__ void zero_kernel(uint4* __restrict__ p, int n16) {
  int i = blockIdx.x * blockDim.x + threadIdx.x;
  if (i < n16) p[i] = make_uint4(0u, 0u, 0u, 0u);
}

// Fold BN into weights: W'[c,k] = W[c,k]*s_c (bf16), bias'_c = b_c*s_c + be_c - m_c*s_c
__global__ void prep_kernel(LayerP p0, LayerP p1, LayerP p2,
                            unsigned short* __restrict__ wsW,
                            float* __restrict__ biasf) {
  const int L = blockIdx.x;
  LayerP p = (L == 0) ? p0 : ((L == 1) ? p1 : p2);
  const int t = threadIdx.x;
  uint2* wdst = (uint2*)(wsW + L * 16384);
  const float4* wsrc = (const float4*)p.W;
  for (int i = 0; i < 16; ++i) {
    int idx4 = t + i * 256;            // 4096 float4 = 128x128
    int c = idx4 >> 5;
    float s = p.g[c] * rsqrtf(p.v[c] + EPSF);
    float4 w = wsrc[idx4];
    wdst[idx4] = make_uint2(pk2(w.x * s, w.y * s), pk2(w.z * s, w.w * s));
  }
  if (t < 128) {
    float s = p.g[t] * rsqrtf(p.v[t] + EPSF);
    biasf[L * 128 + t] = p.b[t] * s + p.be[t] - p.m[t] * s;
  }
}

// Barrier-free persistent encoder: each wave owns independent 32-row tiles.
// x-loads are fully coalesced (instruction i covers bytes [i*1024,(i+1)*1024) of the
// 16KB tile, lane*16 within). Lane then holds col-chunk l31 of rows 2i+hi; a
// wave-local LDS transpose (two 16-row halves through the 4KB wave region) delivers
// the MFMA B-fragments. No cross-tile prefetch: short xr live range -> no spill.
// LDS: [0,98304) swizzled weights (3 layers); [98304,147456) 12x4KB wave regions.
__global__ __launch_bounds__(NTHR, 3)
void enc_kernel(const float* __restrict__ x, const int* __restrict__ batch,
                const unsigned short* __restrict__ wsW, const float* __restrict__ biasf,
                float* __restrict__ seg_sum, int* __restrict__ seg_max,
                u32* __restrict__ seg_cnt, int N, int ntiles) {
  __shared__ __attribute__((aligned(16))) unsigned char lds[98304 + NWAVE * 4096];
  __shared__ __attribute__((aligned(16))) float bias_lds[384];
  const int t = threadIdx.x;
  const int lane = t & 63, wv = t >> 6;
  const int l31 = lane & 31, hi = lane >> 5;
  const int swz = l31 & 15;
  const int xaddr = (lane ^ 32) << 2;  // ds_bpermute byte-addr of partner lane

  // one-time: stage weights global->LDS with chunk^row swizzle
  {
    const uint4* src = (const uint4*)wsW;
#pragma unroll
    for (int i = 0; i < 8; ++i) {
      int idx = t + i * NTHR;          // 6144 x 16B
      int byte = idx << 4;
      int dst = byte ^ (((byte >> 8) & 15) << 4);  // chunk ^= row&15
      *(uint4*)&lds[dst] = src[idx];
    }
  }
  if (t < 384) bias_lds[t] = biasf[t];
  __syncthreads();                      // the only block barrier

  const int hbase = 98304 + wv * 4096;
  const float4* x4 = (const float4*)x;
  const int g0 = blockIdx.x * NWAVE + wv;

  for (int tile = g0; tile < ntiles; tile += STRIDE) {
    // ---- coalesced tile load: instr i = bytes [i*1024,(i+1)*1024), lane*16 within ----
    const bool full = (tile * 32 + 32 <= N);
    float4 xr[16];
    {
      const float4* xt = x4 + (size_t)tile * 1024 + lane;
#pragma unroll
      for (int i = 0; i < 16; ++i)
        xr[i] = full ? xt[i * 64] : make_float4(0.f, 0.f, 0.f, 0.f);
    }
    int rr = tile * 32 + l31;
    const int scur = (rr < N) ? batch[rr] : -1;

    // ---- wave-local transpose: two 16-row halves through the 4KB region ----
    FragU frag[8];
#pragma unroll
    for (int h = 0; h < 2; ++h) {
#pragma unroll
      for (int i = 0; i < 8; ++i) {
        int rowp = 2 * i + hi;           // LDS-local row 0..15 (global row 16h+rowp)
        float4 v = xr[8 * h + i];
        // dest: row rowp, bf16 bytes 8*l31..+8 -> chunk l31>>1 (^rowp swizzle), sub (l31&1)*8
        *(uint2*)&lds[hbase + rowp * 256 + ((((l31 >> 1) ^ rowp) << 4)) + (l31 & 1) * 8] =
            make_uint2(cvtpk(v.x, v.y), cvtpk(v.z, v.w));
      }
      if ((l31 >> 4) == h) {             // my row lives in this half
        const int rowp = l31 & 15;
#pragma unroll
        for (int s = 0; s < 8; ++s)
          frag[s].v = *(const s16x8*)&lds[hbase + rowp * 256 + (((2 * s + hi) ^ rowp) << 4)];
      }
    }

    // ---- 3 fused layers (validated path) ----
    f32x16 accs[4];
#pragma unroll
    for (int L = 0; L < 3; ++L) {
      const int wb = L * 32768 + l31 * 256;
#pragma unroll
      for (int cg = 0; cg < 4; ++cg) {
        f32x16 z = {0,0,0,0,0,0,0,0,0,0,0,0,0,0,0,0};
        accs[cg] = z;
      }
#pragma unroll
      for (int s = 0; s < 8; ++s) {
#pragma unroll
        for (int cg = 0; cg < 4; ++cg) {
          const s16x8 a =
              *(const s16x8*)&lds[wb + cg * 8192 + (((2 * s + hi) ^ swz) << 4)];
          accs[cg] = __builtin_amdgcn_mfma_f32_32x32x16_bf16(a, frag[s].v, accs[cg], 0, 0, 0);
        }
      }
      if (L < 2) {
        // bias + relu, pack (cvt_pk), half-exchange via ds_bpermute
#pragma unroll
        for (int cg = 0; cg < 4; ++cg) {
          float tr[16];
#pragma unroll
          for (int q = 0; q < 4; ++q) {
            int ch = cg * 32 + 4 * hi + 8 * q;   // C/D: c = (r&3) + 8*(r>>2) + 4*hi
            const float4 bb = *(const float4*)&bias_lds[L * 128 + ch];
            tr[4 * q + 0] = fmaxf(accs[cg][4 * q + 0] + bb.x, 0.f);
            tr[4 * q + 1] = fmaxf(accs[cg][4 * q + 1] + bb.y, 0.f);
            tr[4 * q + 2] = fmaxf(accs[cg][4 * q + 2] + bb.z, 0.f);
            tr[4 * q + 3] = fmaxf(accs[cg][4 * q + 3] + bb.w, 0.f);
          }
#pragma unroll
          for (int kh = 0; kh < 2; ++kh) {
            u32 pw0 = cvtpk(tr[8 * kh + 0], tr[8 * kh + 1]);  // c = 16kh+{0,1}+4hi'
            u32 pw1 = cvtpk(tr[8 * kh + 2], tr[8 * kh + 3]);  // c = 16kh+{2,3}+4hi'
            u32 pu0 = cvtpk(tr[8 * kh + 4], tr[8 * kh + 5]);  // c = 16kh+8+{0,1}+4hi'
            u32 pu1 = cvtpk(tr[8 * kh + 6], tr[8 * kh + 7]);  // c = 16kh+8+{2,3}+4hi'
            u32 cw0 = (u32)__builtin_amdgcn_ds_bpermute(xaddr, (int)pw0);
            u32 cw1 = (u32)__builtin_amdgcn_ds_bpermute(xaddr, (int)pw1);
            u32 cu0 = (u32)__builtin_amdgcn_ds_bpermute(xaddr, (int)pu0);
            u32 cu1 = (u32)__builtin_amdgcn_ds_bpermute(xaddr, (int)pu1);
            // target frag[2cg+kh]: u[0,1] = c 16kh+8hi+{0..3}, u[2,3] = +{4..7}
            frag[2 * cg + kh].u[0] = hi ? cu0 : pw0;
            frag[2 * cg + kh].u[1] = hi ? cu1 : pw1;
            frag[2 * cg + kh].u[2] = hi ? pu0 : cw0;
            frag[2 * cg + kh].u[3] = hi ? pu1 : cw1;
          }
        }
      }
    }

    // ---- segment phase: wave-private LDS, two 16-row halves, no barriers ----
    float s0 = 0.f, s1 = 0.f, m0 = 0.f, m1 = 0.f;
    int cur = -1, cnt = 0;
#pragma unroll
    for (int half = 0; half < 2; ++half) {
      if ((l31 >> 4) == half) {  // write my row (l31) with bias+relu applied
#pragma unroll
        for (int cg = 0; cg < 4; ++cg)
#pragma unroll
          for (int q = 0; q < 4; ++q) {
            int ch = cg * 32 + 4 * hi + 8 * q;
            const float4 bb = *(const float4*)&bias_lds[256 + ch];
            float e0 = fmaxf(accs[cg][4 * q + 0] + bb.x, 0.f);
            float e1 = fmaxf(accs[cg][4 * q + 1] + bb.y, 0.f);
            float e2 = fmaxf(accs[cg][4 * q + 2] + bb.z, 0.f);
            float e3 = fmaxf(accs[cg][4 * q + 3] + bb.w, 0.f);
            *(uint2*)&lds[hbase + (l31 & 15) * 256 + ((((cg << 2) + q) ^ swz) << 4) + hi * 8] =
                make_uint2(cvtpk(e0, e1), cvtpk(e2, e3));
          }
      }
      const int rbase = half * 16;
#pragma unroll
      for (int r = 0; r < 16; ++r) {
        int sid = __builtin_amdgcn_readlane(scur, rbase + r);
        if (sid != cur) {
          if (cur >= 0) {
            atomicAdd(&seg_sum[cur * 128 + 2 * lane], s0);
            atomicAdd(&seg_sum[cur * 128 + 2 * lane + 1], s1);
            atomicMax(&seg_max[cur * 128 + 2 * lane], __float_as_int(m0));
            atomicMax(&seg_max[cur * 128 + 2 * lane + 1], __float_as_int(m1));
            if (lane == 0) atomicAdd(&seg_cnt[cur], (u32)cnt);
          }
          s0 = s1 = m0 = m1 = 0.f; cnt = 0; cur = sid;
        }
        if (cur >= 0) {
          u32 pv = *(const u32*)&lds[hbase + r * 256 + ((((lane >> 2) ^ r) & 15) << 4) +
                                     (lane & 3) * 4];
          float v0 = bf2f(pv & 0xffffu);
          float v1 = bf2f(pv >> 16);
          s0 += v0; s1 += v1;
          m0 = fmaxf(m0, v0); m1 = fmaxf(m1, v1);
          ++cnt;
        }
      }
    }
    if (cur >= 0) {  // final flush
      atomicAdd(&seg_sum[cur * 128 + 2 * lane], s0);
      atomicAdd(&seg_sum[cur * 128 + 2 * lane + 1], s1);
      atomicMax(&seg_max[cur * 128 + 2 * lane], __float_as_int(m0));
      atomicMax(&seg_max[cur * 128 + 2 * lane + 1], __float_as_int(m1));
      if (lane == 0) atomicAdd(&seg_cnt[cur], (u32)cnt);
    }
  }
}

// out[s,o] = BN( [sum|max|mean] @ Wo^T + bo )
__global__ __launch_bounds__(128)
void proj_kernel(const float* __restrict__ seg_sum, const unsigned* __restrict__ seg_max,
                 const u32* __restrict__ seg_cnt,
                 const float* __restrict__ Wo, const float* __restrict__ bo,
                 const float* __restrict__ go, const float* __restrict__ beo,
                 const float* __restrict__ mo, const float* __restrict__ vo,
                 float* __restrict__ out) {
  __shared__ __attribute__((aligned(16))) float agg[384];
  __shared__ float part[64];
  const int s = blockIdx.x, t = threadIdx.x;
  float cinv = 1.f / fmaxf((float)seg_cnt[s], 1.f);
  for (int i = t; i < 384; i += 128) {
    float v;
    if (i < 128)      v = seg_sum[s * 128 + i];
    else if (i < 256) v = __uint_as_float(seg_max[s * 128 + i - 128]);
    else              v = seg_sum[s * 128 + i - 256] * cinv;
    agg[i] = v;
  }
  __syncthreads();
  const int o = t & 63, hf = t >> 6;
  const float4* wrow = (const float4*)(Wo + o * 384 + hf * 192);
  float acc = 0.f;
#pragma unroll 8
  for (int k4 = 0; k4 < 48; ++k4) {
    float4 w = wrow[k4];
    float4 a = *(const float4*)&agg[hf * 192 + k4 * 4];
    acc += w.x * a.x + w.y * a.y + w.z * a.z + w.w * a.w;
  }
  if (hf) part[o] = acc;
  __syncthreads();
  if (!hf) {
    acc += part[o];
    float sc = go[o] * rsqrtf(vo[o] + EPSF);
    out[s * 64 + o] = (acc + bo[o] - mo[o]) * sc + beo[o];
  }
}

extern "C" void kernel_launch(void* const* d_in, const int* in_sizes, int n_in,
                              void* d_out, int out_size, void* d_ws, size_t ws_size,
                              hipStream_t stream) {
  (void)n_in; (void)out_size; (void)ws_size;
  const float* x = (const float*)d_in[0];
  const int* batch = (const int*)d_in[1];
  LayerP P0{(const float*)d_in[2],  (const float*)d_in[3],  (const float*)d_in[4],
            (const float*)d_in[5],  (const float*)d_in[6],  (const float*)d_in[7]};
  LayerP P1{(const float*)d_in[8],  (const float*)d_in[9],  (const float*)d_in[10],
            (const float*)d_in[11], (const float*)d_in[12], (const float*)d_in[13]};
  LayerP P2{(const float*)d_in[14], (const float*)d_in[15], (const float*)d_in[16],
            (const float*)d_in[17], (const float*)d_in[18], (const float*)d_in[19]};
  const float* Wo  = (const float*)d_in[20];
  const float* bo  = (const float*)d_in[21];
  const float* go  = (const float*)d_in[22];
  const float* beo = (const float*)d_in[23];
  const float* mo  = (const float*)d_in[24];
  const float* vo  = (const float*)d_in[25];
  const int N = in_sizes[0] / 128;

  char* ws = (char*)d_ws;
  float* seg_sum = (float*)ws;                         // 1 MiB
  int*   seg_max = (int*)(ws + (1u << 20));            // 1 MiB (float bits, >=0)
  u32*   seg_cnt = (u32*)(ws + (2u << 20));            // 8 KiB
  unsigned short* wsW = (unsigned short*)(ws + (2u << 20) + 8192);  // 96 KiB
  float* biasf = (float*)(ws + (2u << 20) + 8192 + 98304);          // 1.5 KiB

  const int n16 = ((2 << 20) + 8192) / 16;
  zero_kernel<<<(n16 + 255) / 256, 256, 0, stream>>>((uint4*)d_ws, n16);
  prep_kernel<<<3, 256, 0, stream>>>(P0, P1, P2, wsW, biasf);
  const int ntiles = (N + 31) / 32;
  enc_kernel<<<NBLK, NTHR, 0, stream>>>(x, batch, wsW, biasf, seg_sum, seg_max, seg_cnt,
                                        N, ntiles);
  proj_kernel<<<NSEG, 128, 0, stream>>>(seg_sum, (const unsigned*)seg_max, seg_cnt,
                                        Wo, bo, go, beo, mo, vo, (float*)d_out);
}

// Round 10
// 156.481 us; speedup vs baseline: 1.5502x; 1.0058x over previous
//
#include <hip/hip_runtime.h>

#define EPSF 1e-5f
#define NSEG 2048
#define NTHR 768     // 12 waves
#define NWAVE 12
#define NBLK 256

typedef short s16x8 __attribute__((ext_vector_type(8)));
typedef float f32x16 __attribute__((ext_vector_type(16)));
typedef unsigned u32;

__device__ __forceinline__ u32 f2bfu(float f) {
  u32 u = __float_as_uint(f);
  u += 0x7FFFu + ((u >> 16) & 1u);  // RNE; no NaN/Inf in data
  return u >> 16;
}
__device__ __forceinline__ u32 pk2(float a, float b) {  // host-prep path only
  return f2bfu(a) | (f2bfu(b) << 16);
}
// v_cvt_pk_bf16_f32: dst = {lo=bf16(a), hi=bf16(b)} — 1 VALU op
__device__ __forceinline__ u32 cvtpk(float a, float b) {
  u32 r;
  asm("v_cvt_pk_bf16_f32 %0, %1, %2" : "=v"(r) : "v"(a), "v"(b));
  return r;
}
__device__ __forceinline__ float bf2f(u32 h) {
  return __uint_as_float(h << 16);
}

union FragU { s16x8 v; u32 u[4]; };

struct LayerP { const float *W, *b, *g, *be, *m, *v; };

__global__ void zero_kernel(uint4* __restrict__ p, int n16) {
  int i = blockIdx.x * blockDim.x + threadIdx.x;
  if (i < n16) p[i] = make_uint4(0u, 0u, 0u, 0u);
}

// Fold BN into weights: W'[c,k] = W[c,k]*s_c (bf16), bias'_c = b_c*s_c + be_c - m_c*s_c
__global__ void prep_kernel(LayerP p0, LayerP p1, LayerP p2,
                            unsigned short* __restrict__ wsW,
                            float* __restrict__ biasf) {
  const int L = blockIdx.x;
  LayerP p = (L == 0) ? p0 : ((L == 1) ? p1 : p2);
  const int t = threadIdx.x;
  uint2* wdst = (uint2*)(wsW + L * 16384);
  const float4* wsrc = (const float4*)p.W;
  for (int i = 0; i < 16; ++i) {
    int idx4 = t + i * 256;            // 4096 float4 = 128x128
    int c = idx4 >> 5;
    float s = p.g[c] * rsqrtf(p.v[c] + EPSF);
    float4 w = wsrc[idx4];
    wdst[idx4] = make_uint2(pk2(w.x * s, w.y * s), pk2(w.z * s, w.w * s));
  }
  if (t < 128) {
    float s = p.g[t] * rsqrtf(p.v[t] + EPSF);
    biasf[L * 128 + t] = p.b[t] * s + p.be[t] - p.m[t] * s;
  }
}

// Barrier-free persistent encoder. Each wave owns ~5-6 CONSECUTIVE 32-row tiles
// (contiguous rows < avg segment length 244), carrying the open segment run in
// registers across tiles -> flushes (global atomics) drop ~3.4x vs strided mapping.
// x-loads fully coalesced (instr i = bytes [i*1024,(i+1)*1024), lane*16 within);
// wave-local LDS transpose delivers MFMA B-frags.
// LDS: [0,98304) swizzled weights (3 layers); [98304,147456) 12x4KB wave regions.
__global__ __launch_bounds__(NTHR, 3)
void enc_kernel(const float* __restrict__ x, const int* __restrict__ batch,
                const unsigned short* __restrict__ wsW, const float* __restrict__ biasf,
                float* __restrict__ seg_sum, int* __restrict__ seg_max,
                u32* __restrict__ seg_cnt, int N, int ntiles) {
  __shared__ __attribute__((aligned(16))) unsigned char lds[98304 + NWAVE * 4096];
  __shared__ __attribute__((aligned(16))) float bias_lds[384];
  const int t = threadIdx.x;
  const int lane = t & 63, wv = t >> 6;
  const int l31 = lane & 31, hi = lane >> 5;
  const int swz = l31 & 15;
  const int xaddr = (lane ^ 32) << 2;  // ds_bpermute byte-addr of partner lane

  // one-time: stage weights global->LDS with chunk^row swizzle
  {
    const uint4* src = (const uint4*)wsW;
#pragma unroll
    for (int i = 0; i < 8; ++i) {
      int idx = t + i * NTHR;          // 6144 x 16B
      int byte = idx << 4;
      int dst = byte ^ (((byte >> 8) & 15) << 4);  // chunk ^= row&15
      *(uint4*)&lds[dst] = src[idx];
    }
  }
  if (t < 384) bias_lds[t] = biasf[t];
  __syncthreads();                      // the only block barrier

  const int hbase = 98304 + wv * 4096;
  const float4* x4 = (const float4*)x;

  // contiguous balanced tile range for this wave
  const int w = blockIdx.x * NWAVE + wv;         // 0..3071
  const int TW = NBLK * NWAVE;                   // 3072
  const int base = ntiles / TW, rem = ntiles % TW;
  const int t0 = w * base + (w < rem ? w : rem);
  const int t1 = t0 + base + (w < rem ? 1 : 0);

  // open segment run, carried across tiles
  float s0 = 0.f, s1 = 0.f, m0 = 0.f, m1 = 0.f;
  int cur = -1, cnt = 0;

  for (int tile = t0; tile < t1; ++tile) {
    // ---- coalesced tile load: instr i = bytes [i*1024,(i+1)*1024), lane*16 within ----
    const bool full = (tile * 32 + 32 <= N);
    float4 xr[16];
    {
      const float4* xt = x4 + (size_t)tile * 1024 + lane;
#pragma unroll
      for (int i = 0; i < 16; ++i)
        xr[i] = full ? xt[i * 64] : make_float4(0.f, 0.f, 0.f, 0.f);
    }
    int rr = tile * 32 + l31;
    const int scur = (rr < N) ? batch[rr] : -1;

    // ---- wave-local transpose: two 16-row halves through the 4KB region ----
    FragU frag[8];
#pragma unroll
    for (int h = 0; h < 2; ++h) {
#pragma unroll
      for (int i = 0; i < 8; ++i) {
        int rowp = 2 * i + hi;           // LDS-local row 0..15 (global row 16h+rowp)
        float4 v = xr[8 * h + i];
        *(uint2*)&lds[hbase + rowp * 256 + ((((l31 >> 1) ^ rowp) << 4)) + (l31 & 1) * 8] =
            make_uint2(cvtpk(v.x, v.y), cvtpk(v.z, v.w));
      }
      if ((l31 >> 4) == h) {             // my row lives in this half
        const int rowp = l31 & 15;
#pragma unroll
        for (int s = 0; s < 8; ++s)
          frag[s].v = *(const s16x8*)&lds[hbase + rowp * 256 + (((2 * s + hi) ^ rowp) << 4)];
      }
    }

    // ---- 3 fused layers (validated path) ----
    f32x16 accs[4];
#pragma unroll
    for (int L = 0; L < 3; ++L) {
      const int wb = L * 32768 + l31 * 256;
#pragma unroll
      for (int cg = 0; cg < 4; ++cg) {
        f32x16 z = {0,0,0,0,0,0,0,0,0,0,0,0,0,0,0,0};
        accs[cg] = z;
      }
#pragma unroll
      for (int s = 0; s < 8; ++s) {
#pragma unroll
        for (int cg = 0; cg < 4; ++cg) {
          const s16x8 a =
              *(const s16x8*)&lds[wb + cg * 8192 + (((2 * s + hi) ^ swz) << 4)];
          accs[cg] = __builtin_amdgcn_mfma_f32_32x32x16_bf16(a, frag[s].v, accs[cg], 0, 0, 0);
        }
      }
      if (L < 2) {
        // bias + relu, pack (cvt_pk), half-exchange via ds_bpermute
#pragma unroll
        for (int cg = 0; cg < 4; ++cg) {
          float tr[16];
#pragma unroll
          for (int q = 0; q < 4; ++q) {
            int ch = cg * 32 + 4 * hi + 8 * q;   // C/D: c = (r&3) + 8*(r>>2) + 4*hi
            const float4 bb = *(const float4*)&bias_lds[L * 128 + ch];
            tr[4 * q + 0] = fmaxf(accs[cg][4 * q + 0] + bb.x, 0.f);
            tr[4 * q + 1] = fmaxf(accs[cg][4 * q + 1] + bb.y, 0.f);
            tr[4 * q + 2] = fmaxf(accs[cg][4 * q + 2] + bb.z, 0.f);
            tr[4 * q + 3] = fmaxf(accs[cg][4 * q + 3] + bb.w, 0.f);
          }
#pragma unroll
          for (int kh = 0; kh < 2; ++kh) {
            u32 pw0 = cvtpk(tr[8 * kh + 0], tr[8 * kh + 1]);
            u32 pw1 = cvtpk(tr[8 * kh + 2], tr[8 * kh + 3]);
            u32 pu0 = cvtpk(tr[8 * kh + 4], tr[8 * kh + 5]);
            u32 pu1 = cvtpk(tr[8 * kh + 6], tr[8 * kh + 7]);
            u32 cw0 = (u32)__builtin_amdgcn_ds_bpermute(xaddr, (int)pw0);
            u32 cw1 = (u32)__builtin_amdgcn_ds_bpermute(xaddr, (int)pw1);
            u32 cu0 = (u32)__builtin_amdgcn_ds_bpermute(xaddr, (int)pu0);
            u32 cu1 = (u32)__builtin_amdgcn_ds_bpermute(xaddr, (int)pu1);
            frag[2 * cg + kh].u[0] = hi ? cu0 : pw0;
            frag[2 * cg + kh].u[1] = hi ? cu1 : pw1;
            frag[2 * cg + kh].u[2] = hi ? pu0 : cw0;
            frag[2 * cg + kh].u[3] = hi ? pu1 : cw1;
          }
        }
      }
    }

    // ---- segment phase: wave-private LDS; run carried across tiles, flush on change ----
#pragma unroll
    for (int half = 0; half < 2; ++half) {
      if ((l31 >> 4) == half) {  // write my row (l31) with bias+relu applied
#pragma unroll
        for (int cg = 0; cg < 4; ++cg)
#pragma unroll
          for (int q = 0; q < 4; ++q) {
            int ch = cg * 32 + 4 * hi + 8 * q;
            const float4 bb = *(const float4*)&bias_lds[256 + ch];
            float e0 = fmaxf(accs[cg][4 * q + 0] + bb.x, 0.f);
            float e1 = fmaxf(accs[cg][4 * q + 1] + bb.y, 0.f);
            float e2 = fmaxf(accs[cg][4 * q + 2] + bb.z, 0.f);
            float e3 = fmaxf(accs[cg][4 * q + 3] + bb.w, 0.f);
            *(uint2*)&lds[hbase + (l31 & 15) * 256 + ((((cg << 2) + q) ^ swz) << 4) + hi * 8] =
                make_uint2(cvtpk(e0, e1), cvtpk(e2, e3));
          }
      }
      const int rbase = half * 16;
#pragma unroll
      for (int r = 0; r < 16; ++r) {
        int sid = __builtin_amdgcn_readlane(scur, rbase + r);
        if (sid != cur) {
          if (cur >= 0) {
            atomicAdd(&seg_sum[cur * 128 + 2 * lane], s0);
            atomicAdd(&seg_sum[cur * 128 + 2 * lane + 1], s1);
            atomicMax(&seg_max[cur * 128 + 2 * lane], __float_as_int(m0));
            atomicMax(&seg_max[cur * 128 + 2 * lane + 1], __float_as_int(m1));
            if (lane == 0) atomicAdd(&seg_cnt[cur], (u32)cnt);
          }
          s0 = s1 = m0 = m1 = 0.f; cnt = 0; cur = sid;
        }
        if (cur >= 0) {
          u32 pv = *(const u32*)&lds[hbase + r * 256 + ((((lane >> 2) ^ r) & 15) << 4) +
                                     (lane & 3) * 4];
          float v0 = bf2f(pv & 0xffffu);
          float v1 = bf2f(pv >> 16);
          s0 += v0; s1 += v1;
          m0 = fmaxf(m0, v0); m1 = fmaxf(m1, v1);
          ++cnt;
        }
      }
    }
  }
  if (cur >= 0) {  // final flush for the wave's open run
    atomicAdd(&seg_sum[cur * 128 + 2 * lane], s0);
    atomicAdd(&seg_sum[cur * 128 + 2 * lane + 1], s1);
    atomicMax(&seg_max[cur * 128 + 2 * lane], __float_as_int(m0));
    atomicMax(&seg_max[cur * 128 + 2 * lane + 1], __float_as_int(m1));
    if (lane == 0) atomicAdd(&seg_cnt[cur], (u32)cnt);
  }
}

// out[s,o] = BN( [sum|max|mean] @ Wo^T + bo )
__global__ __launch_bounds__(128)
void proj_kernel(const float* __restrict__ seg_sum, const unsigned* __restrict__ seg_max,
                 const u32* __restrict__ seg_cnt,
                 const float* __restrict__ Wo, const float* __restrict__ bo,
                 const float* __restrict__ go, const float* __restrict__ beo,
                 const float* __restrict__ mo, const float* __restrict__ vo,
                 float* __restrict__ out) {
  __shared__ __attribute__((aligned(16))) float agg[384];
  __shared__ float part[64];
  const int s = blockIdx.x, t = threadIdx.x;
  float cinv = 1.f / fmaxf((float)seg_cnt[s], 1.f);
  for (int i = t; i < 384; i += 128) {
    float v;
    if (i < 128)      v = seg_sum[s * 128 + i];
    else if (i < 256) v = __uint_as_float(seg_max[s * 128 + i - 128]);
    else              v = seg_sum[s * 128 + i - 256] * cinv;
    agg[i] = v;
  }
  __syncthreads();
  const int o = t & 63, hf = t >> 6;
  const float4* wrow = (const float4*)(Wo + o * 384 + hf * 192);
  float acc = 0.f;
#pragma unroll 8
  for (int k4 = 0; k4 < 48; ++k4) {
    float4 w = wrow[k4];
    float4 a = *(const float4*)&agg[hf * 192 + k4 * 4];
    acc += w.x * a.x + w.y * a.y + w.z * a.z + w.w * a.w;
  }
  if (hf) part[o] = acc;
  __syncthreads();
  if (!hf) {
    acc += part[o];
    float sc = go[o] * rsqrtf(vo[o] + EPSF);
    out[s * 64 + o] = (acc + bo[o] - mo[o]) * sc + beo[o];
  }
}

extern "C" void kernel_launch(void* const* d_in, const int* in_sizes, int n_in,
                              void* d_out, int out_size, void* d_ws, size_t ws_size,
                              hipStream_t stream) {
  (void)n_in; (void)out_size; (void)ws_size;
  const float* x = (const float*)d_in[0];
  const int* batch = (const int*)d_in[1];
  LayerP P0{(const float*)d_in[2],  (const float*)d_in[3],  (const float*)d_in[4],
            (const float*)d_in[5],  (const float*)d_in[6],  (const float*)d_in[7]};
  LayerP P1{(const float*)d_in[8],  (const float*)d_in[9],  (const float*)d_in[10],
            (const float*)d_in[11], (const float*)d_in[12], (const float*)d_in[13]};
  LayerP P2{(const float*)d_in[14], (const float*)d_in[15], (const float*)d_in[16],
            (const float*)d_in[17], (const float*)d_in[18], (const float*)d_in[19]};
  const float* Wo  = (const float*)d_in[20];
  const float* bo  = (const float*)d_in[21];
  const float* go  = (const float*)d_in[22];
  const float* beo = (const float*)d_in[23];
  const float* mo  = (const float*)d_in[24];
  const float* vo  = (const float*)d_in[25];
  const int N = in_sizes[0] / 128;

  char* ws = (char*)d_ws;
  float* seg_sum = (float*)ws;                         // 1 MiB
  int*   seg_max = (int*)(ws + (1u << 20));            // 1 MiB (float bits, >=0)
  u32*   seg_cnt = (u32*)(ws + (2u << 20));            // 8 KiB
  unsigned short* wsW = (unsigned short*)(ws + (2u << 20) + 8192);  // 96 KiB
  float* biasf = (float*)(ws + (2u << 20) + 8192 + 98304);          // 1.5 KiB

  const int n16 = ((2 << 20) + 8192) / 16;
  zero_kernel<<<(n16 + 255) / 256, 256, 0, stream>>>((uint4*)d_ws, n16);
  prep_kernel<<<3, 256, 0, stream>>>(P0, P1, P2, wsW, biasf);
  const int ntiles = (N + 31) / 32;
  enc_kernel<<<NBLK, NTHR, 0, stream>>>(x, batch, wsW, biasf, seg_sum, seg_max, seg_cnt,
                                        N, ntiles);
  proj_kernel<<<NSEG, 128, 0, stream>>>(seg_sum, (const unsigned*)seg_max, seg_cnt,
                                        Wo, bo, go, beo, mo, vo, (float*)d_out);
}

// Round 11
// 114.053 us; speedup vs baseline: 2.1269x; 1.3720x over previous
//
#include <hip/hip_runtime.h>

#define EPSF 1e-5f
#define NSEG 2048
#define NTHR 768     // 12 waves
#define NWAVE 12
#define NBLK 256

typedef short s16x8 __attribute__((ext_vector_type(8)));
typedef float f32x16 __attribute__((ext_vector_type(16)));
typedef unsigned u32;

__device__ __forceinline__ u32 f2bfu(float f) {
  u32 u = __float_as_uint(f);
  u += 0x7FFFu + ((u >> 16) & 1u);  // RNE; no NaN/Inf in data
  return u >> 16;
}
__device__ __forceinline__ u32 pk2(float a, float b) {  // host-prep path only
  return f2bfu(a) | (f2bfu(b) << 16);
}
// v_cvt_pk_bf16_f32: dst = {lo=bf16(a), hi=bf16(b)} — 1 VALU op
__device__ __forceinline__ u32 cvtpk(float a, float b) {
  u32 r;
  asm("v_cvt_pk_bf16_f32 %0, %1, %2" : "=v"(r) : "v"(a), "v"(b));
  return r;
}
__device__ __forceinline__ float bf2f(u32 h) {
  return __uint_as_float(h << 16);
}

union FragU { s16x8 v; u32 u[4]; };

struct LayerP { const float *W, *b, *g, *be, *m, *v; };

__global__ void zero_kernel(uint4* __restrict__ p, int n16) {
  int i = blockIdx.x * blockDim.x + threadIdx.x;
  if (i < n16) p[i] = make_uint4(0u, 0u, 0u, 0u);
}

// Fold BN into weights: W'[c,k] = W[c,k]*s_c (bf16), bias'_c = b_c*s_c + be_c - m_c*s_c
__global__ void prep_kernel(LayerP p0, LayerP p1, LayerP p2,
                            unsigned short* __restrict__ wsW,
                            float* __restrict__ biasf) {
  const int L = blockIdx.x;
  LayerP p = (L == 0) ? p0 : ((L == 1) ? p1 : p2);
  const int t = threadIdx.x;
  uint2* wdst = (uint2*)(wsW + L * 16384);
  const float4* wsrc = (const float4*)p.W;
  for (int i = 0; i < 16; ++i) {
    int idx4 = t + i * 256;            // 4096 float4 = 128x128
    int c = idx4 >> 5;
    float s = p.g[c] * rsqrtf(p.v[c] + EPSF);
    float4 w = wsrc[idx4];
    wdst[idx4] = make_uint2(pk2(w.x * s, w.y * s), pk2(w.z * s, w.w * s));
  }
  if (t < 128) {
    float s = p.g[t] * rsqrtf(p.v[t] + EPSF);
    biasf[L * 128 + t] = p.b[t] * s + p.be[t] - p.m[t] * s;
  }
}

// Barrier-free persistent encoder, contiguous tile ranges per wave.
// L0/L1: D = W'.h (lane = x-row) with ds_bpermute half-exchange between layers.
// L2: OPERAND-SWAPPED mfma(frag, w) -> D = h2.W2'^T with lane = OUTPUT CHANNEL and
//     x-rows in registers: segment sum/max reduce IN-REGISTER (no LDS round-trip,
//     no serial 32-iter loop), then one bpermute combines hi-halves, atomics flush.
// LDS: [0,98304) swizzled weights (3 layers); [98304,147456) 12x4KB transpose regions.
__global__ __launch_bounds__(NTHR, 3)
void enc_kernel(const float* __restrict__ x, const int* __restrict__ batch,
                const unsigned short* __restrict__ wsW, const float* __restrict__ biasf,
                float* __restrict__ seg_sum, int* __restrict__ seg_max,
                u32* __restrict__ seg_cnt, int N, int ntiles) {
  __shared__ __attribute__((aligned(16))) unsigned char lds[98304 + NWAVE * 4096];
  __shared__ __attribute__((aligned(16))) float bias_lds[384];
  const int t = threadIdx.x;
  const int lane = t & 63, wv = t >> 6;
  const int l31 = lane & 31, hi = lane >> 5;
  const int swz = l31 & 15;
  const int xaddr = (lane ^ 32) << 2;  // ds_bpermute byte-addr of partner lane

  // one-time: stage weights global->LDS with chunk^row swizzle
  {
    const uint4* src = (const uint4*)wsW;
#pragma unroll
    for (int i = 0; i < 8; ++i) {
      int idx = t + i * NTHR;          // 6144 x 16B
      int byte = idx << 4;
      int dst = byte ^ (((byte >> 8) & 15) << 4);  // chunk ^= row&15
      *(uint4*)&lds[dst] = src[idx];
    }
  }
  if (t < 384) bias_lds[t] = biasf[t];
  __syncthreads();                      // the only block barrier

  // L2 bias per-lane (channel cg*32+l31), hoisted out of the tile loop
  float bias2[4];
#pragma unroll
  for (int cg = 0; cg < 4; ++cg) bias2[cg] = bias_lds[256 + cg * 32 + l31];

  const int hbase = 98304 + wv * 4096;
  const float4* x4 = (const float4*)x;

  // contiguous balanced tile range for this wave
  const int w = blockIdx.x * NWAVE + wv;         // 0..3071
  const int TW = NBLK * NWAVE;                   // 3072
  const int base = ntiles / TW, rem = ntiles % TW;
  const int t0 = w * base + (w < rem ? w : rem);
  const int t1 = t0 + base + (w < rem ? 1 : 0);

  for (int tile = t0; tile < t1; ++tile) {
    // ---- coalesced tile load: instr i = bytes [i*1024,(i+1)*1024), lane*16 within ----
    const bool full = (tile * 32 + 32 <= N);
    float4 xr[16];
    {
      const float4* xt = x4 + (size_t)tile * 1024 + lane;
#pragma unroll
      for (int i = 0; i < 16; ++i)
        xr[i] = full ? xt[i * 64] : make_float4(0.f, 0.f, 0.f, 0.f);
    }
    int rr = tile * 32 + l31;
    const int scur = (rr < N) ? batch[rr] : -1;

    // ---- wave-local transpose: two 16-row halves through the 4KB region ----
    FragU frag[8];
#pragma unroll
    for (int h = 0; h < 2; ++h) {
#pragma unroll
      for (int i = 0; i < 8; ++i) {
        int rowp = 2 * i + hi;           // LDS-local row 0..15 (global row 16h+rowp)
        float4 v = xr[8 * h + i];
        *(uint2*)&lds[hbase + rowp * 256 + ((((l31 >> 1) ^ rowp) << 4)) + (l31 & 1) * 8] =
            make_uint2(cvtpk(v.x, v.y), cvtpk(v.z, v.w));
      }
      if ((l31 >> 4) == h) {             // my row lives in this half
        const int rowp = l31 & 15;
#pragma unroll
        for (int s = 0; s < 8; ++s)
          frag[s].v = *(const s16x8*)&lds[hbase + rowp * 256 + (((2 * s + hi) ^ rowp) << 4)];
      }
    }

    // ---- 3 fused layers ----
    f32x16 accs[4];
#pragma unroll
    for (int L = 0; L < 3; ++L) {
      const int wb = L * 32768 + l31 * 256;
#pragma unroll
      for (int cg = 0; cg < 4; ++cg) {
        f32x16 z = {0,0,0,0,0,0,0,0,0,0,0,0,0,0,0,0};
        accs[cg] = z;
      }
#pragma unroll
      for (int s = 0; s < 8; ++s) {
#pragma unroll
        for (int cg = 0; cg < 4; ++cg) {
          const s16x8 a =
              *(const s16x8*)&lds[wb + cg * 8192 + (((2 * s + hi) ^ swz) << 4)];
          if (L < 2)
            accs[cg] = __builtin_amdgcn_mfma_f32_32x32x16_bf16(a, frag[s].v, accs[cg], 0, 0, 0);
          else  // swapped: D = h2 . W2'^T, lane = out-channel, rows in regs
            accs[cg] = __builtin_amdgcn_mfma_f32_32x32x16_bf16(frag[s].v, a, accs[cg], 0, 0, 0);
        }
      }
      if (L < 2) {
        // bias + relu, pack (cvt_pk), half-exchange via ds_bpermute
#pragma unroll
        for (int cg = 0; cg < 4; ++cg) {
          float tr[16];
#pragma unroll
          for (int q = 0; q < 4; ++q) {
            int ch = cg * 32 + 4 * hi + 8 * q;   // C/D: c = (r&3) + 8*(r>>2) + 4*hi
            const float4 bb = *(const float4*)&bias_lds[L * 128 + ch];
            tr[4 * q + 0] = fmaxf(accs[cg][4 * q + 0] + bb.x, 0.f);
            tr[4 * q + 1] = fmaxf(accs[cg][4 * q + 1] + bb.y, 0.f);
            tr[4 * q + 2] = fmaxf(accs[cg][4 * q + 2] + bb.z, 0.f);
            tr[4 * q + 3] = fmaxf(accs[cg][4 * q + 3] + bb.w, 0.f);
          }
#pragma unroll
          for (int kh = 0; kh < 2; ++kh) {
            u32 pw0 = cvtpk(tr[8 * kh + 0], tr[8 * kh + 1]);
            u32 pw1 = cvtpk(tr[8 * kh + 2], tr[8 * kh + 3]);
            u32 pu0 = cvtpk(tr[8 * kh + 4], tr[8 * kh + 5]);
            u32 pu1 = cvtpk(tr[8 * kh + 6], tr[8 * kh + 7]);
            u32 cw0 = (u32)__builtin_amdgcn_ds_bpermute(xaddr, (int)pw0);
            u32 cw1 = (u32)__builtin_amdgcn_ds_bpermute(xaddr, (int)pw1);
            u32 cu0 = (u32)__builtin_amdgcn_ds_bpermute(xaddr, (int)pu0);
            u32 cu1 = (u32)__builtin_amdgcn_ds_bpermute(xaddr, (int)pu1);
            frag[2 * cg + kh].u[0] = hi ? cu0 : pw0;
            frag[2 * cg + kh].u[1] = hi ? cu1 : pw1;
            frag[2 * cg + kh].u[2] = hi ? pu0 : cw0;
            frag[2 * cg + kh].u[3] = hi ? pu1 : cw1;
          }
        }
      }
    }

    // ---- segment phase, in-register (lane = channel cg*32+l31; 16 rows in regs) ----
    // row of accs[cg][rg] (global within tile) = (rg&3) + 8*(rg>>2) + 4*hi
    const int nvalid = min(N - tile * 32, 32);
    const int sid0 = __builtin_amdgcn_readlane(scur, 0);
    const int sidL = __builtin_amdgcn_readlane(scur, nvalid - 1);
#pragma unroll
    for (int cg = 0; cg < 4; ++cg)
#pragma unroll
      for (int rg = 0; rg < 16; ++rg)
        accs[cg][rg] = fmaxf(accs[cg][rg] + bias2[cg], 0.f);

    if (nvalid == 32 && sid0 == sidL) {
      // fast path: whole tile in one segment
#pragma unroll
      for (int cg = 0; cg < 4; ++cg) {
        float s = 0.f, mx = 0.f;
#pragma unroll
        for (int rg = 0; rg < 16; ++rg) { s += accs[cg][rg]; mx = fmaxf(mx, accs[cg][rg]); }
        float ps = __int_as_float(__builtin_amdgcn_ds_bpermute(xaddr, __float_as_int(s)));
        float pm = __int_as_float(__builtin_amdgcn_ds_bpermute(xaddr, __float_as_int(mx)));
        s += ps; mx = fmaxf(mx, pm);
        if (!hi) {
          atomicAdd(&seg_sum[sid0 * 128 + cg * 32 + l31], s);
          atomicMax(&seg_max[sid0 * 128 + cg * 32 + l31], __float_as_int(mx));
        }
      }
      if (lane == 0) atomicAdd(&seg_cnt[sid0], 32u);
    } else {
      // slow path: per-row sids via bpermute, loop over the (small) sid range
      int srow[16];
#pragma unroll
      for (int rg = 0; rg < 16; ++rg) {
        int m = (rg & 3) + 8 * (rg >> 2) + 4 * hi;
        srow[rg] = __builtin_amdgcn_ds_bpermute(m << 2, scur);
      }
      for (int sg = sid0; sg <= sidL; ++sg) {
#pragma unroll
        for (int cg = 0; cg < 4; ++cg) {
          float s = 0.f, mx = 0.f;
#pragma unroll
          for (int rg = 0; rg < 16; ++rg) {
            float v = (srow[rg] == sg) ? accs[cg][rg] : 0.f;
            s += v; mx = fmaxf(mx, v);
          }
          float ps = __int_as_float(__builtin_amdgcn_ds_bpermute(xaddr, __float_as_int(s)));
          float pm = __int_as_float(__builtin_amdgcn_ds_bpermute(xaddr, __float_as_int(mx)));
          s += ps; mx = fmaxf(mx, pm);
          if (!hi) {
            atomicAdd(&seg_sum[sg * 128 + cg * 32 + l31], s);
            atomicMax(&seg_max[sg * 128 + cg * 32 + l31], __float_as_int(mx));
          }
        }
        u32 c = (u32)__popcll(__ballot(hi == 0 && scur == sg));
        if (lane == 0) atomicAdd(&seg_cnt[sg], c);
      }
    }
  }
}

// out[s,o] = BN( [sum|max|mean] @ Wo^T + bo )
__global__ __launch_bounds__(128)
void proj_kernel(const float* __restrict__ seg_sum, const unsigned* __restrict__ seg_max,
                 const u32* __restrict__ seg_cnt,
                 const float* __restrict__ Wo, const float* __restrict__ bo,
                 const float* __restrict__ go, const float* __restrict__ beo,
                 const float* __restrict__ mo, const float* __restrict__ vo,
                 float* __restrict__ out) {
  __shared__ __attribute__((aligned(16))) float agg[384];
  __shared__ float part[64];
  const int s = blockIdx.x, t = threadIdx.x;
  float cinv = 1.f / fmaxf((float)seg_cnt[s], 1.f);
  for (int i = t; i < 384; i += 128) {
    float v;
    if (i < 128)      v = seg_sum[s * 128 + i];
    else if (i < 256) v = __uint_as_float(seg_max[s * 128 + i - 128]);
    else              v = seg_sum[s * 128 + i - 256] * cinv;
    agg[i] = v;
  }
  __syncthreads();
  const int o = t & 63, hf = t >> 6;
  const float4* wrow = (const float4*)(Wo + o * 384 + hf * 192);
  float acc = 0.f;
#pragma unroll 8
  for (int k4 = 0; k4 < 48; ++k4) {
    float4 w = wrow[k4];
    float4 a = *(const float4*)&agg[hf * 192 + k4 * 4];
    acc += w.x * a.x + w.y * a.y + w.z * a.z + w.w * a.w;
  }
  if (hf) part[o] = acc;
  __syncthreads();
  if (!hf) {
    acc += part[o];
    float sc = go[o] * rsqrtf(vo[o] + EPSF);
    out[s * 64 + o] = (acc + bo[o] - mo[o]) * sc + beo[o];
  }
}

extern "C" void kernel_launch(void* const* d_in, const int* in_sizes, int n_in,
                              void* d_out, int out_size, void* d_ws, size_t ws_size,
                              hipStream_t stream) {
  (void)n_in; (void)out_size; (void)ws_size;
  const float* x = (const float*)d_in[0];
  const int* batch = (const int*)d_in[1];
  LayerP P0{(const float*)d_in[2],  (const float*)d_in[3],  (const float*)d_in[4],
            (const float*)d_in[5],  (const float*)d_in[6],  (const float*)d_in[7]};
  LayerP P1{(const float*)d_in[8],  (const float*)d_in[9],  (const float*)d_in[10],
            (const float*)d_in[11], (const float*)d_in[12], (const float*)d_in[13]};
  LayerP P2{(const float*)d_in[14], (const float*)d_in[15], (const float*)d_in[16],
            (const float*)d_in[17], (const float*)d_in[18], (const float*)d_in[19]};
  const float* Wo  = (const float*)d_in[20];
  const float* bo  = (const float*)d_in[21];
  const float* go  = (const float*)d_in[22];
  const float* beo = (const float*)d_in[23];
  const float* mo  = (const float*)d_in[24];
  const float* vo  = (const float*)d_in[25];
  const int N = in_sizes[0] / 128;

  char* ws = (char*)d_ws;
  float* seg_sum = (float*)ws;                         // 1 MiB
  int*   seg_max = (int*)(ws + (1u << 20));            // 1 MiB (float bits, >=0)
  u32*   seg_cnt = (u32*)(ws + (2u << 20));            // 8 KiB
  unsigned short* wsW = (unsigned short*)(ws + (2u << 20) + 8192);  // 96 KiB
  float* biasf = (float*)(ws + (2u << 20) + 8192 + 98304);          // 1.5 KiB

  const int n16 = ((2 << 20) + 8192) / 16;
  zero_kernel<<<(n16 + 255) / 256, 256, 0, stream>>>((uint4*)d_ws, n16);
  prep_kernel<<<3, 256, 0, stream>>>(P0, P1, P2, wsW, biasf);
  const int ntiles = (N + 31) / 32;
  enc_kernel<<<NBLK, NTHR, 0, stream>>>(x, batch, wsW, biasf, seg_sum, seg_max, seg_cnt,
                                        N, ntiles);
  proj_kernel<<<NSEG, 128, 0, stream>>>(seg_sum, (const unsigned*)seg_max, seg_cnt,
                                        Wo, bo, go, beo, mo, vo, (float*)d_out);
}